// Round 18
// baseline (372.510 us; speedup 1.0000x reference)
//
#include <hip/hip_runtime.h>

typedef unsigned short u16;
typedef __attribute__((ext_vector_type(8))) short short8;
typedef __attribute__((ext_vector_type(8))) unsigned short ushort8;
typedef __attribute__((ext_vector_type(4))) unsigned short ushort4v;
typedef __attribute__((ext_vector_type(4))) float f32x4;

static constexpr int Cdim = 768;
static constexpr int Hdim = 3072;
static constexpr int Edim = 8;
static constexpr int Ntok = 4096;   // B*T
static constexpr int DRc  = 24;
static constexpr int NSLOT = Ntok * 2;  // 8192
static constexpr int NCHUNK = 8;
static constexpr int CCH = Cdim / NCHUNK;  // 96
static constexpr int KS2 = 3;              // fc2 split-K factor
static constexpr int KC2 = Hdim / KS2;     // 1024
static constexpr int MAXROWS = 71;         // sum ceil(n_e/128) <= 64+7
static constexpr int NPREP = 4608;         // 2304 tiles per layer (64x128)

// ---- workspace layout (bytes) ----
static constexpr size_t OFF_XB   = 0;                          // x bf16: 6,291,456
static constexpr size_t OFF_W1T  = 6291456;                    // [E][H][C] bf16: 37,748,736
static constexpr size_t OFF_W2T  = 44040192;                   // [E][C][H] bf16: 37,748,736
static constexpr size_t OFF_HBUF = 81788928;                   // 8192*3072*2 = 50,331,648
// xT/part alias hbuf (dead before fc1); ybuf aliases W1T (dead after fc1)
static constexpr size_t OFF_XT   = OFF_HBUF;                   // f32 [C][N]: 12,582,912
static constexpr size_t OFF_PART = OFF_HBUF + 12582912;        // f32 [8][33][N]: 4,325,376
static constexpr size_t OFF_YB   = OFF_W1T;                    // bf16 [3][NSLOT][C]: 37,748,736
static constexpr size_t OFF_TOK  = 132120576;                  // E*N*4 = 131,072
static constexpr size_t OFF_RM   = 132251648;                  // rowmap int[71]
static constexpr size_t OFF_NR   = 132252160;                  // nrows int[1]
static constexpr size_t OFF_CNT  = 132382720;                  // 8*4
static constexpr size_t OFF_OFFS = 132382752;                  // 8*4
static constexpr size_t OFF_TSLOT= 132382784;                  // int4 [Ntok]: 65,536
static constexpr size_t OFF_TG   = 132448320;                  // float2 [Ntok]: 32,768

__device__ __forceinline__ u16 f2bf(float f) {
  unsigned u = __builtin_bit_cast(unsigned, f);
  u += 0x7fffu + ((u >> 16) & 1u);          // round-to-nearest-even
  return (u16)(u >> 16);
}

__device__ __forceinline__ float bf2f(u16 v) {
  unsigned u = ((unsigned)v) << 16;
  return __builtin_bit_cast(float, u);
}

// async global->LDS, 16B per lane (HW: wave-uniform LDS base + lane*16)
__device__ __forceinline__ void gld16(const u16* g, u16* l) {
  __builtin_amdgcn_global_load_lds((const __attribute__((address_space(1))) unsigned int*)g,
                                   (__attribute__((address_space(3))) unsigned int*)l,
                                   16, 0, 0);
}

// bijective chunked XCD remap (m204)
__device__ __forceinline__ int xcd_remap(int p, int nwg) {
  int q = nwg >> 3, rem = nwg & 7;
  int x = p & 7, i = p >> 3;
  return (x < rem ? x * (q + 1) : rem * (q + 1) + (x - rem) * q) + i;
}

// ---------- prep: x -> bf16 [N][C]  AND  x -> f32 transpose [C][N] ----------
__global__ __launch_bounds__(256)
void prep_x2_kernel(const float* __restrict__ x, u16* __restrict__ x16,
                    float* __restrict__ xT) {
  __shared__ float tile[64][65];
  const int c0 = blockIdx.x * 64;
  const int t0 = blockIdx.y * 64;
  const int tid = threadIdx.x;
  const int row = tid >> 4, col = (tid & 15) * 4;
  #pragma unroll
  for (int i = 0; i < 4; i++) {
    int r = row + i * 16;
    size_t idx = (size_t)(t0 + r) * Cdim + c0 + col;
    float4 v = *(const float4*)(x + idx);
    tile[r][col + 0] = v.x; tile[r][col + 1] = v.y;
    tile[r][col + 2] = v.z; tile[r][col + 3] = v.w;
    ushort4v o = { f2bf(v.x), f2bf(v.y), f2bf(v.z), f2bf(v.w) };
    *reinterpret_cast<ushort4v*>(x16 + idx) = o;
  }
  __syncthreads();
  const int c = tid >> 2, tg = (tid & 3) * 16;
  #pragma unroll
  for (int q = 0; q < 4; q++) {
    float4 w;
    w.x = tile[tg + q * 4 + 0][c];
    w.y = tile[tg + q * 4 + 1][c];
    w.z = tile[tg + q * 4 + 2][c];
    w.w = tile[tg + q * 4 + 3][c];
    *reinterpret_cast<float4*>(xT + (size_t)(c0 + c) * Ntok + t0 + tg + q * 4) = w;
  }
}

// ---------- prep W: 64r x 128c tile, u32 column-pair LDS ----------
template<int R, int CCOL>
__device__ __forceinline__ void prep_wt_body(const float* __restrict__ wf,
                                             const float* __restrict__ wsl,
                                             const float* __restrict__ hf, float m,
                                             u16* __restrict__ outw, int e, int r0, int c0,
                                             unsigned* lds) {
  const size_t base = (size_t)e * R * CCOL;
  const int t = threadIdx.x;
  {
    const int rp = t >> 5;            // 0..7
    const int col4 = (t & 31) * 4;    // 0..124
    const int c2w = (t & 31) * 2;
    #pragma unroll
    for (int i = 0; i < 8; i++) {
      int r = i * 8 + rp;
      size_t idx = base + (size_t)(r0 + r) * CCOL + c0 + col4;
      float4 a = *(const float4*)(wf + idx);
      float4 b = *(const float4*)(wsl + idx);
      float4 h = *(const float4*)(hf + idx);
      unsigned u0 = (unsigned)f2bf(fmaf(m, b.x, a.x) + h.x)
                  | ((unsigned)f2bf(fmaf(m, b.y, a.y) + h.y) << 16);
      unsigned u1 = (unsigned)f2bf(fmaf(m, b.z, a.z) + h.z)
                  | ((unsigned)f2bf(fmaf(m, b.w, a.w) + h.w) << 16);
      lds[c2w * 65 + r] = u0;
      lds[(c2w + 1) * 65 + r] = u1;
    }
  }
  __syncthreads();
  {
    const int c2 = t >> 2;            // 0..63 (column pair)
    const int rseg = (t & 3) * 16;    // 16-row segment
    const unsigned* cp = lds + c2 * 65 + rseg;
    unsigned in4[16];
    #pragma unroll
    for (int j = 0; j < 4; j++)
      *reinterpret_cast<uint4*>(&in4[j * 4]) = *reinterpret_cast<const uint4*>(cp + j * 4);
    unsigned lo[8], hi[8];
    #pragma unroll
    for (int j = 0; j < 8; j++) {
      unsigned a = in4[2 * j], b = in4[2 * j + 1];
      lo[j] = (a & 0xffffu) | (b << 16);
      hi[j] = (a >> 16) | (b & 0xffff0000u);
    }
    size_t ob = ((size_t)e * CCOL + c0 + 2 * c2) * R + r0 + rseg;   // u16 units
    *reinterpret_cast<uint4*>(outw + ob)          = *reinterpret_cast<const uint4*>(&lo[0]);
    *reinterpret_cast<uint4*>(outw + ob + 8)      = *reinterpret_cast<const uint4*>(&lo[4]);
    *reinterpret_cast<uint4*>(outw + ob + R)      = *reinterpret_cast<const uint4*>(&hi[0]);
    *reinterpret_cast<uint4*>(outw + ob + R + 8)  = *reinterpret_cast<const uint4*>(&hi[4]);
  }
}

__global__ __launch_bounds__(256)
void prep_wt2_kernel(const float* __restrict__ wf1, const float* __restrict__ ws1,
                     const float* __restrict__ hf1, const float* __restrict__ mg1,
                     u16* __restrict__ o1,
                     const float* __restrict__ wf2, const float* __restrict__ ws2,
                     const float* __restrict__ hf2, const float* __restrict__ mg2,
                     u16* __restrict__ o2) {
  __shared__ unsigned lds[64 * 65];    // 16,640 B
  int bid = blockIdx.x;
  if (bid < 2304) {      // layer1: R=768 -> 12 r-tiles, CCOL=3072 -> 24 c-tiles
    int e = bid / 288, rem = bid % 288;
    int xx = rem % 12, yy = rem / 12;
    prep_wt_body<768, 3072>(wf1, ws1, hf1, mg1[e], o1, e, xx * 64, yy * 128, lds);
  } else {               // layer2: R=3072 -> 48 r-tiles, CCOL=768 -> 6 c-tiles
    bid -= 2304;
    int e = bid / 288, rem = bid % 288;
    int xx = rem % 48, yy = rem / 48;
    prep_wt_body<3072, 768>(wf2, ws2, hf2, mg2[e], o2, e, xx * 64, yy * 128, lds);
  }
}

// ---------- router part 1 ----------
__global__ __launch_bounds__(256)
void logits_part_kernel(const float* __restrict__ xT, const float* __restrict__ router_w,
                        const float* __restrict__ probe_w, float* __restrict__ part) {
  const int t = blockIdx.x * 256 + threadIdx.x;
  const int cB = blockIdx.y * CCH;
  float racc[Edim] = {};
  float pacc[DRc] = {};
  float sacc = 0.f;
  for (int ci = 0; ci < CCH; ci++) {
    int c = cB + ci;
    float xv = xT[(size_t)c * Ntok + t];
    sacc += xv;
    #pragma unroll
    for (int ee = 0; ee < Edim; ee++) racc[ee] = fmaf(xv, router_w[ee * Cdim + c], racc[ee]);
    #pragma unroll
    for (int d = 0; d < DRc; d++) pacc[d] = fmaf(xv, probe_w[d * Cdim + c], pacc[d]);
  }
  float* pb = part + (size_t)blockIdx.y * 33 * Ntok + t;
  #pragma unroll
  for (int ee = 0; ee < Edim; ee++) pb[(size_t)ee * Ntok] = racc[ee];
  #pragma unroll
  for (int d = 0; d < DRc; d++) pb[(size_t)(8 + d) * Ntok] = pacc[d];
  pb[(size_t)32 * Ntok] = sacc;
}

// ---------- router part 2 ----------
__global__ __launch_bounds__(256)
void router_fin_kernel(const float* __restrict__ part, const float* __restrict__ emb,
                       const float* __restrict__ fatigue, const float* __restrict__ energy,
                       int* __restrict__ counts, int* __restrict__ tok_list,
                       int4* __restrict__ tokslot, float2* __restrict__ tokgate) {
  const int t = blockIdx.x * 256 + threadIdx.x;
  float v[33];
  #pragma unroll
  for (int o = 0; o < 33; o++) {
    float s = 0.f;
    #pragma unroll
    for (int ch = 0; ch < NCHUNK; ch++)
      s += part[((size_t)ch * 33 + o) * Ntok + t];
    v[o] = s;
  }
  const float* racc = v;
  const float* pacc = v + 8;
  float proxy = v[32] / 768.f;
  float pn2 = 0.f;
  #pragma unroll
  for (int d = 0; d < DRc; d++) pn2 += pacc[d] * pacc[d];
  float pnorm = sqrtf(pn2);
  float logitv[Edim];
  #pragma unroll
  for (int ee = 0; ee < Edim; ee++) {
    float g2 = 0.f, dote = 0.f;
    #pragma unroll
    for (int d = 0; d < DRc; d++) {
      float ev = emb[ee * DRc + d];
      g2 += ev * ev;
      dote += pacc[d] * ev;
    }
    float gain = sqrtf(g2);
    float align = dote / (fmaxf(pnorm, 1e-12f) * fmaxf(gain, 1e-12f));
    logitv[ee] = racc[ee] + 0.02f * proxy * (1.f + gain) + 0.02f * align
               + 0.1f * energy[ee] - 0.1f * fatigue[ee];
  }
  int e0 = 0; float b0v = logitv[0];
  #pragma unroll
  for (int ee = 1; ee < Edim; ee++) if (logitv[ee] > b0v) { b0v = logitv[ee]; e0 = ee; }
  int e1 = -1; float b1v = -3.4e38f;
  #pragma unroll
  for (int ee = 0; ee < Edim; ee++) if (ee != e0 && logitv[ee] > b1v) { b1v = logitv[ee]; e1 = ee; }
  float texp = expf(b1v - b0v);
  float g0 = 1.f / (1.f + texp);
  float g1 = texp / (1.f + texp);
  int p0 = atomicAdd(&counts[e0], 1);
  tok_list[e0 * Ntok + p0] = t;
  int p1 = atomicAdd(&counts[e1], 1);
  tok_list[e1 * Ntok + p1] = t;
  tokslot[t] = make_int4(e0, p0, e1, p1);
  tokgate[t] = make_float2(g0, g1);
}

// ---------- offsets + compacted row worklist ----------
__global__ void offsets_kernel(const int* __restrict__ counts, int* __restrict__ offs,
                               int* __restrict__ rowmap, int* __restrict__ nrows) {
  if (threadIdx.x == 0) {
    int r = 0, nr = 0;
    for (int e = 0; e < Edim; e++) {
      offs[e] = r;
      int ne = counts[e];
      for (int tb = 0; tb < ne; tb += 128) rowmap[nr++] = (e << 16) | (tb >> 7);
      r += ne;
    }
    nrows[0] = nr;
  }
}

// ---------- fc1: h = relu(x @ W1 + b1)^2, 128tok x 64h tile, SINGLE-buffer ----------
__global__ __launch_bounds__(256)
void fc1_kernel(const u16* __restrict__ x16, const u16* __restrict__ W1T,
                const float* __restrict__ b1, const int* __restrict__ counts,
                const int* __restrict__ offs, const int* __restrict__ tok_list,
                const int* __restrict__ rowmap, const int* __restrict__ nrows,
                u16* __restrict__ h_buf) {
  const int l = xcd_remap(blockIdx.x, MAXROWS * 48);
  const int r = l / 48;
  if (r >= nrows[0]) return;
  const int hB = l % 48;
  const int rm = rowmap[r];
  const int e = rm >> 16;
  const int tokBase = (rm & 0xffff) << 7;
  const int n_e = counts[e];
  const int hBase = hB * 64;
  __shared__ u16 As[4096];     // 128 rows x 32 k
  __shared__ u16 Bs[2048];     // 64 hcols x 32 k
  __shared__ int toks[128];
  const int tid = threadIdx.x;
  if (tid < 128) {
    int s = tokBase + tid;
    toks[tid] = (s < n_e) ? tok_list[e * Ntok + s] : 0;
  }
  __syncthreads();
  const int lane = tid & 63, wv = tid >> 6;
  const int sRow = lane >> 2, sSlot = lane & 3;
  const int kbOff = (sSlot ^ ((sRow >> 1) & 3)) * 8;
  const int rA0 = wv * 16 + sRow, rA1 = 64 + rA0;     // A rows (tokens)
  const u16* pA0 = x16 + (size_t)toks[rA0] * Cdim + kbOff;
  const u16* pA1 = x16 + (size_t)toks[rA1] * Cdim + kbOff;
  const u16* pB0 = W1T + ((size_t)e * Hdim + hBase + rA0) * Cdim + kbOff;  // 64 h rows
  const int stOff = wv * 512 + lane * 8;
  const int fr = lane & 15;
  const int qsw = (((lane >> 4) ^ ((fr >> 1) & 3))) * 8;
  f32x4 acc[2][4] = {};
  for (int it = 0; it < 24; it++) {
    int k0 = it * 32;
    gld16(pA0 + k0, &As[stOff]);
    gld16(pA1 + k0, &As[2048 + stOff]);
    gld16(pB0 + k0, &Bs[stOff]);
    __syncthreads();
    short8 aF[2], bF[4];
    #pragma unroll
    for (int m = 0; m < 2; m++)
      aF[m] = *reinterpret_cast<const short8*>(&As[(wv * 32 + m * 16 + fr) * 32 + qsw]);
    #pragma unroll
    for (int n = 0; n < 4; n++)
      bF[n] = *reinterpret_cast<const short8*>(&Bs[(n * 16 + fr) * 32 + qsw]);
    #pragma unroll
    for (int m = 0; m < 2; m++)
      #pragma unroll
      for (int n = 0; n < 4; n++)
        acc[m][n] = __builtin_amdgcn_mfma_f32_16x16x32_bf16(aF[m], bF[n], acc[m][n], 0, 0, 0);
    __syncthreads();
  }
  const int rq = (lane >> 4) * 4;
  float bias[4];
  #pragma unroll
  for (int n = 0; n < 4; n++) bias[n] = b1[(size_t)e * Hdim + hBase + n * 16 + fr];
  const int rowB = offs[e] + tokBase;
  #pragma unroll
  for (int m = 0; m < 2; m++) {
    #pragma unroll
    for (int j = 0; j < 4; j++) {
      int rl = wv * 32 + m * 16 + rq + j;
      if (tokBase + rl < n_e) {
        size_t rb = (size_t)(rowB + rl) * Hdim + hBase + fr;
        #pragma unroll
        for (int n = 0; n < 4; n++) {
          float v = fmaxf(acc[m][n][j] + bias[n], 0.f);
          h_buf[rb + n * 16] = f2bf(v * v);
        }
      }
    }
  }
}

// ---------- fc2: ybuf[kch][slot] = h @ W2T[kch] (+b2 on kch0), 128tok x 64c tile ----------
// 4 waves stacked over tokens; grid MAXROWS*36 (3 kch x 12 cB) -> ~10 blocks/CU.
__global__ __launch_bounds__(256)
void fc2_kernel(const u16* __restrict__ h_buf, const u16* __restrict__ W2T,
                const float* __restrict__ b2, const int* __restrict__ counts,
                const int* __restrict__ offs, const int* __restrict__ rowmap,
                const int* __restrict__ nrows, u16* __restrict__ ybuf) {
  const int l = xcd_remap(blockIdx.x, MAXROWS * 36);
  const int r = l / 36;
  if (r >= nrows[0]) return;
  const int xb = l % 36;
  const int rm = rowmap[r];
  const int e = rm >> 16;
  const int tokBase = (rm & 0xffff) << 7;
  const int n_e = counts[e];
  const int kch = xb / 12;                 // 0..KS2-1
  const int cBase = (xb % 12) * 64;
  const size_t kOff = (size_t)kch * KC2;
  __shared__ u16 As[4096];     // 128 tok x 32 k
  __shared__ u16 Bs[2048];     // 64 c x 32 k
  const int tid = threadIdx.x;
  const int lane = tid & 63, wv = tid >> 6;
  const int sRow = lane >> 2, sSlot = lane & 3;
  const int kbOff = (sSlot ^ ((sRow >> 1) & 3)) * 8;
  const int rA0 = wv * 16 + sRow, rA1 = 64 + rA0;
  const int slotB = offs[e] + tokBase;
  const int s0 = min(slotB + rA0, NSLOT - 1);
  const int s1 = min(slotB + rA1, NSLOT - 1);
  const u16* pA0 = h_buf + (size_t)s0 * Hdim + kOff + kbOff;
  const u16* pA1 = h_buf + (size_t)s1 * Hdim + kOff + kbOff;
  const u16* pB0 = W2T + ((size_t)e * Cdim + cBase + rA0) * Hdim + kOff + kbOff;
  const int stOff = wv * 512 + lane * 8;
  const int fr = lane & 15;
  const int qsw = (((lane >> 4) ^ ((fr >> 1) & 3))) * 8;
  f32x4 acc[2][4] = {};
  for (int it = 0; it < KC2 / 32; it++) {
    int k0 = it * 32;
    gld16(pA0 + k0, &As[stOff]);
    gld16(pA1 + k0, &As[2048 + stOff]);
    gld16(pB0 + k0, &Bs[stOff]);
    __syncthreads();
    short8 aF[2], bF[4];
    #pragma unroll
    for (int m = 0; m < 2; m++)
      aF[m] = *reinterpret_cast<const short8*>(&As[(wv * 32 + m * 16 + fr) * 32 + qsw]);
    #pragma unroll
    for (int n = 0; n < 4; n++)
      bF[n] = *reinterpret_cast<const short8*>(&Bs[(n * 16 + fr) * 32 + qsw]);
    #pragma unroll
    for (int m = 0; m < 2; m++)
      #pragma unroll
      for (int n = 0; n < 4; n++)
        acc[m][n] = __builtin_amdgcn_mfma_f32_16x16x32_bf16(aF[m], bF[n], acc[m][n], 0, 0, 0);
    __syncthreads();
  }
  const int rq = (lane >> 4) * 4;
  float bias[4];
  #pragma unroll
  for (int n = 0; n < 4; n++)
    bias[n] = (kch == 0) ? b2[(size_t)e * Cdim + cBase + n * 16 + fr] : 0.f;
  u16* yb = ybuf + (size_t)kch * NSLOT * Cdim;
  #pragma unroll
  for (int m = 0; m < 2; m++) {
    #pragma unroll
    for (int j = 0; j < 4; j++) {
      int rl = wv * 32 + m * 16 + rq + j;
      if (tokBase + rl < n_e) {
        u16* ob = yb + (size_t)(slotB + rl) * Cdim + cBase + fr;
        #pragma unroll
        for (int n = 0; n < 4; n++)
          ob[n * 16] = f2bf(acc[m][n][j] + bias[n]);
      }
    }
  }
}

// ---------- gather ----------
__global__ __launch_bounds__(256)
void gather_kernel(const u16* __restrict__ ybuf, const int4* __restrict__ tokslot,
                   const float2* __restrict__ tokgate, const int* __restrict__ offs,
                   float* __restrict__ out) {
  const int gid = blockIdx.x * 256 + threadIdx.x;
  const int t = gid / 192;
  const int c4 = (gid - t * 192) * 4;
  int4 ts = tokslot[t];
  float2 g = tokgate[t];
  size_t s0 = (size_t)(offs[ts.x] + ts.y) * Cdim + c4;
  size_t s1 = (size_t)(offs[ts.z] + ts.w) * Cdim + c4;
  const size_t K1 = (size_t)NSLOT * Cdim;
  float acc0[4] = {}, acc1[4] = {};
  #pragma unroll
  for (int k = 0; k < KS2; k++) {
    ushort4v a = *reinterpret_cast<const ushort4v*>(ybuf + k * K1 + s0);
    ushort4v b = *reinterpret_cast<const ushort4v*>(ybuf + k * K1 + s1);
    #pragma unroll
    for (int j = 0; j < 4; j++) { acc0[j] += bf2f(a[j]); acc1[j] += bf2f(b[j]); }
  }
  float4 o;
  o.x = g.x * acc0[0] + g.y * acc1[0];
  o.y = g.x * acc0[1] + g.y * acc1[1];
  o.z = g.x * acc0[2] + g.y * acc1[2];
  o.w = g.x * acc0[3] + g.y * acc1[3];
  *reinterpret_cast<float4*>(out + (size_t)t * Cdim + c4) = o;
}

extern "C" void kernel_launch(void* const* d_in, const int* in_sizes, int n_in,
                              void* d_out, int out_size, void* d_ws, size_t ws_size,
                              hipStream_t stream) {
  const float* x        = (const float*)d_in[0];
  const float* router_w = (const float*)d_in[1];
  const float* probe_w  = (const float*)d_in[2];
  const float* emb      = (const float*)d_in[3];
  const float* fatigue  = (const float*)d_in[4];
  const float* energy   = (const float*)d_in[5];
  const float* wf1      = (const float*)d_in[6];
  const float* ws1      = (const float*)d_in[7];
  const float* hf1      = (const float*)d_in[8];
  const float* mg1      = (const float*)d_in[9];
  const float* b1       = (const float*)d_in[10];
  const float* wf2      = (const float*)d_in[11];
  const float* ws2      = (const float*)d_in[12];
  const float* hf2      = (const float*)d_in[13];
  const float* mg2      = (const float*)d_in[14];
  const float* b2       = (const float*)d_in[15];
  float* out = (float*)d_out;
  char* ws = (char*)d_ws;

  u16*    x16       = (u16*)(ws + OFF_XB);
  u16*    W1T       = (u16*)(ws + OFF_W1T);
  u16*    W2T       = (u16*)(ws + OFF_W2T);
  u16*    hbuf      = (u16*)(ws + OFF_HBUF);
  float*  xT        = (float*)(ws + OFF_XT);
  float*  part      = (float*)(ws + OFF_PART);
  u16*    ybuf      = (u16*)(ws + OFF_YB);
  int*    tok_list  = (int*)(ws + OFF_TOK);
  int*    rowmap    = (int*)(ws + OFF_RM);
  int*    nrows     = (int*)(ws + OFF_NR);
  int*    counts    = (int*)(ws + OFF_CNT);
  int*    offs      = (int*)(ws + OFF_OFFS);
  int4*   tokslot   = (int4*)(ws + OFF_TSLOT);
  float2* tokgate   = (float2*)(ws + OFF_TG);

  hipMemsetAsync(counts, 0, 64, stream);

  prep_x2_kernel<<<dim3(Cdim / 64, Ntok / 64), 256, 0, stream>>>(x, x16, xT);
  logits_part_kernel<<<dim3(Ntok / 256, NCHUNK), 256, 0, stream>>>(xT, router_w, probe_w, part);
  router_fin_kernel<<<Ntok / 256, 256, 0, stream>>>(part, emb, fatigue, energy,
                                                    counts, tok_list, tokslot, tokgate);
  prep_wt2_kernel<<<NPREP, 256, 0, stream>>>(wf1, ws1, hf1, mg1, W1T,
                                             wf2, ws2, hf2, mg2, W2T);
  offsets_kernel<<<1, 64, 0, stream>>>(counts, offs, rowmap, nrows);
  fc1_kernel<<<MAXROWS * 48, 256, 0, stream>>>(x16, W1T, b1, counts, offs, tok_list,
                                               rowmap, nrows, hbuf);
  fc2_kernel<<<MAXROWS * 36, 256, 0, stream>>>(hbuf, W2T, b2, counts, offs,
                                               rowmap, nrows, ybuf);
  gather_kernel<<<Ntok * 192 / 256, 256, 0, stream>>>(ybuf, tokslot, tokgate, offs, out);
  (void)in_sizes; (void)n_in; (void)out_size; (void)ws_size;
}

// Round 19
// 345.900 us; speedup vs baseline: 1.0769x; 1.0769x over previous
//
#include <hip/hip_runtime.h>

typedef unsigned short u16;
typedef __attribute__((ext_vector_type(8))) short short8;
typedef __attribute__((ext_vector_type(8))) unsigned short ushort8;
typedef __attribute__((ext_vector_type(4))) unsigned short ushort4v;
typedef __attribute__((ext_vector_type(4))) float f32x4;

static constexpr int Cdim = 768;
static constexpr int Hdim = 3072;
static constexpr int Edim = 8;
static constexpr int Ntok = 4096;   // B*T
static constexpr int DRc  = 24;
static constexpr int NSLOT = Ntok * 2;  // 8192
static constexpr int NCHUNK = 8;
static constexpr int CCH = Cdim / NCHUNK;  // 96
static constexpr int KS2 = 3;              // fc2 split-K factor
static constexpr int KC2 = Hdim / KS2;     // 1024
static constexpr int MAXROWS = 71;         // sum ceil(n_e/128) <= 64+7
static constexpr int NPREP = 4608;         // 2304 tiles per layer (64x128)

// ---- workspace layout (bytes) ----
static constexpr size_t OFF_XB   = 0;                          // x bf16: 6,291,456
static constexpr size_t OFF_W1T  = 6291456;                    // [E][H][C] bf16: 37,748,736
static constexpr size_t OFF_W2T  = 44040192;                   // [E][C][H] bf16: 37,748,736
static constexpr size_t OFF_HBUF = 81788928;                   // 8192*3072*2 = 50,331,648
// xT/part alias hbuf (dead before fc1); ybuf aliases W1T (dead after fc1)
static constexpr size_t OFF_XT   = OFF_HBUF;                   // f32 [C][N]: 12,582,912
static constexpr size_t OFF_PART = OFF_HBUF + 12582912;        // f32 [8][33][N]: 4,325,376
static constexpr size_t OFF_YB   = OFF_W1T;                    // bf16 [3][NSLOT][C]: 37,748,736
static constexpr size_t OFF_TOK  = 132120576;                  // E*N*4 = 131,072
static constexpr size_t OFF_RM   = 132251648;                  // rowmap int[71]
static constexpr size_t OFF_NR   = 132252160;                  // nrows int[1]
static constexpr size_t OFF_CNT  = 132382720;                  // 8*4
static constexpr size_t OFF_OFFS = 132382752;                  // 8*4
static constexpr size_t OFF_TSLOT= 132382784;                  // int4 [Ntok]: 65,536
static constexpr size_t OFF_TG   = 132448320;                  // float2 [Ntok]: 32,768

__device__ __forceinline__ u16 f2bf(float f) {
  unsigned u = __builtin_bit_cast(unsigned, f);
  u += 0x7fffu + ((u >> 16) & 1u);          // round-to-nearest-even
  return (u16)(u >> 16);
}

__device__ __forceinline__ float bf2f(u16 v) {
  unsigned u = ((unsigned)v) << 16;
  return __builtin_bit_cast(float, u);
}

// async global->LDS, 16B per lane (HW: wave-uniform LDS base + lane*16)
__device__ __forceinline__ void gld16(const u16* g, u16* l) {
  __builtin_amdgcn_global_load_lds((const __attribute__((address_space(1))) unsigned int*)g,
                                   (__attribute__((address_space(3))) unsigned int*)l,
                                   16, 0, 0);
}

// bijective chunked XCD remap (m204)
__device__ __forceinline__ int xcd_remap(int p, int nwg) {
  int q = nwg >> 3, rem = nwg & 7;
  int x = p & 7, i = p >> 3;
  return (x < rem ? x * (q + 1) : rem * (q + 1) + (x - rem) * q) + i;
}

// ---------- prep: x -> bf16 [N][C]  AND  x -> f32 transpose [C][N] ----------
__global__ __launch_bounds__(256)
void prep_x2_kernel(const float* __restrict__ x, u16* __restrict__ x16,
                    float* __restrict__ xT) {
  __shared__ float tile[64][65];
  const int c0 = blockIdx.x * 64;
  const int t0 = blockIdx.y * 64;
  const int tid = threadIdx.x;
  const int row = tid >> 4, col = (tid & 15) * 4;
  #pragma unroll
  for (int i = 0; i < 4; i++) {
    int r = row + i * 16;
    size_t idx = (size_t)(t0 + r) * Cdim + c0 + col;
    float4 v = *(const float4*)(x + idx);
    tile[r][col + 0] = v.x; tile[r][col + 1] = v.y;
    tile[r][col + 2] = v.z; tile[r][col + 3] = v.w;
    ushort4v o = { f2bf(v.x), f2bf(v.y), f2bf(v.z), f2bf(v.w) };
    *reinterpret_cast<ushort4v*>(x16 + idx) = o;
  }
  __syncthreads();
  const int c = tid >> 2, tg = (tid & 3) * 16;
  #pragma unroll
  for (int q = 0; q < 4; q++) {
    float4 w;
    w.x = tile[tg + q * 4 + 0][c];
    w.y = tile[tg + q * 4 + 1][c];
    w.z = tile[tg + q * 4 + 2][c];
    w.w = tile[tg + q * 4 + 3][c];
    *reinterpret_cast<float4*>(xT + (size_t)(c0 + c) * Ntok + t0 + tg + q * 4) = w;
  }
}

// ---------- prep W: 64r x 128c tile, u32 column-pair LDS ----------
template<int R, int CCOL>
__device__ __forceinline__ void prep_wt_body(const float* __restrict__ wf,
                                             const float* __restrict__ wsl,
                                             const float* __restrict__ hf, float m,
                                             u16* __restrict__ outw, int e, int r0, int c0,
                                             unsigned* lds) {
  const size_t base = (size_t)e * R * CCOL;
  const int t = threadIdx.x;
  {
    const int rp = t >> 5;            // 0..7
    const int col4 = (t & 31) * 4;    // 0..124
    const int c2w = (t & 31) * 2;
    #pragma unroll
    for (int i = 0; i < 8; i++) {
      int r = i * 8 + rp;
      size_t idx = base + (size_t)(r0 + r) * CCOL + c0 + col4;
      float4 a = *(const float4*)(wf + idx);
      float4 b = *(const float4*)(wsl + idx);
      float4 h = *(const float4*)(hf + idx);
      unsigned u0 = (unsigned)f2bf(fmaf(m, b.x, a.x) + h.x)
                  | ((unsigned)f2bf(fmaf(m, b.y, a.y) + h.y) << 16);
      unsigned u1 = (unsigned)f2bf(fmaf(m, b.z, a.z) + h.z)
                  | ((unsigned)f2bf(fmaf(m, b.w, a.w) + h.w) << 16);
      lds[c2w * 65 + r] = u0;
      lds[(c2w + 1) * 65 + r] = u1;
    }
  }
  __syncthreads();
  {
    const int c2 = t >> 2;            // 0..63 (column pair)
    const int rseg = (t & 3) * 16;    // 16-row segment
    const unsigned* cp = lds + c2 * 65 + rseg;
    unsigned in4[16];
    #pragma unroll
    for (int j = 0; j < 4; j++)
      *reinterpret_cast<uint4*>(&in4[j * 4]) = *reinterpret_cast<const uint4*>(cp + j * 4);
    unsigned lo[8], hi[8];
    #pragma unroll
    for (int j = 0; j < 8; j++) {
      unsigned a = in4[2 * j], b = in4[2 * j + 1];
      lo[j] = (a & 0xffffu) | (b << 16);
      hi[j] = (a >> 16) | (b & 0xffff0000u);
    }
    size_t ob = ((size_t)e * CCOL + c0 + 2 * c2) * R + r0 + rseg;   // u16 units
    *reinterpret_cast<uint4*>(outw + ob)          = *reinterpret_cast<const uint4*>(&lo[0]);
    *reinterpret_cast<uint4*>(outw + ob + 8)      = *reinterpret_cast<const uint4*>(&lo[4]);
    *reinterpret_cast<uint4*>(outw + ob + R)      = *reinterpret_cast<const uint4*>(&hi[0]);
    *reinterpret_cast<uint4*>(outw + ob + R + 8)  = *reinterpret_cast<const uint4*>(&hi[4]);
  }
}

__global__ __launch_bounds__(256)
void prep_wt2_kernel(const float* __restrict__ wf1, const float* __restrict__ ws1,
                     const float* __restrict__ hf1, const float* __restrict__ mg1,
                     u16* __restrict__ o1,
                     const float* __restrict__ wf2, const float* __restrict__ ws2,
                     const float* __restrict__ hf2, const float* __restrict__ mg2,
                     u16* __restrict__ o2) {
  __shared__ unsigned lds[64 * 65];    // 16,640 B
  int bid = blockIdx.x;
  if (bid < 2304) {      // layer1: R=768 -> 12 r-tiles, CCOL=3072 -> 24 c-tiles
    int e = bid / 288, rem = bid % 288;
    int xx = rem % 12, yy = rem / 12;
    prep_wt_body<768, 3072>(wf1, ws1, hf1, mg1[e], o1, e, xx * 64, yy * 128, lds);
  } else {               // layer2: R=3072 -> 48 r-tiles, CCOL=768 -> 6 c-tiles
    bid -= 2304;
    int e = bid / 288, rem = bid % 288;
    int xx = rem % 48, yy = rem / 48;
    prep_wt_body<3072, 768>(wf2, ws2, hf2, mg2[e], o2, e, xx * 64, yy * 128, lds);
  }
}

// ---------- router part 1 ----------
__global__ __launch_bounds__(256)
void logits_part_kernel(const float* __restrict__ xT, const float* __restrict__ router_w,
                        const float* __restrict__ probe_w, float* __restrict__ part) {
  const int t = blockIdx.x * 256 + threadIdx.x;
  const int cB = blockIdx.y * CCH;
  float racc[Edim] = {};
  float pacc[DRc] = {};
  float sacc = 0.f;
  for (int ci = 0; ci < CCH; ci++) {
    int c = cB + ci;
    float xv = xT[(size_t)c * Ntok + t];
    sacc += xv;
    #pragma unroll
    for (int ee = 0; ee < Edim; ee++) racc[ee] = fmaf(xv, router_w[ee * Cdim + c], racc[ee]);
    #pragma unroll
    for (int d = 0; d < DRc; d++) pacc[d] = fmaf(xv, probe_w[d * Cdim + c], pacc[d]);
  }
  float* pb = part + (size_t)blockIdx.y * 33 * Ntok + t;
  #pragma unroll
  for (int ee = 0; ee < Edim; ee++) pb[(size_t)ee * Ntok] = racc[ee];
  #pragma unroll
  for (int d = 0; d < DRc; d++) pb[(size_t)(8 + d) * Ntok] = pacc[d];
  pb[(size_t)32 * Ntok] = sacc;
}

// ---------- router part 2 ----------
__global__ __launch_bounds__(256)
void router_fin_kernel(const float* __restrict__ part, const float* __restrict__ emb,
                       const float* __restrict__ fatigue, const float* __restrict__ energy,
                       int* __restrict__ counts, int* __restrict__ tok_list,
                       int4* __restrict__ tokslot, float2* __restrict__ tokgate) {
  const int t = blockIdx.x * 256 + threadIdx.x;
  float v[33];
  #pragma unroll
  for (int o = 0; o < 33; o++) {
    float s = 0.f;
    #pragma unroll
    for (int ch = 0; ch < NCHUNK; ch++)
      s += part[((size_t)ch * 33 + o) * Ntok + t];
    v[o] = s;
  }
  const float* racc = v;
  const float* pacc = v + 8;
  float proxy = v[32] / 768.f;
  float pn2 = 0.f;
  #pragma unroll
  for (int d = 0; d < DRc; d++) pn2 += pacc[d] * pacc[d];
  float pnorm = sqrtf(pn2);
  float logitv[Edim];
  #pragma unroll
  for (int ee = 0; ee < Edim; ee++) {
    float g2 = 0.f, dote = 0.f;
    #pragma unroll
    for (int d = 0; d < DRc; d++) {
      float ev = emb[ee * DRc + d];
      g2 += ev * ev;
      dote += pacc[d] * ev;
    }
    float gain = sqrtf(g2);
    float align = dote / (fmaxf(pnorm, 1e-12f) * fmaxf(gain, 1e-12f));
    logitv[ee] = racc[ee] + 0.02f * proxy * (1.f + gain) + 0.02f * align
               + 0.1f * energy[ee] - 0.1f * fatigue[ee];
  }
  int e0 = 0; float b0v = logitv[0];
  #pragma unroll
  for (int ee = 1; ee < Edim; ee++) if (logitv[ee] > b0v) { b0v = logitv[ee]; e0 = ee; }
  int e1 = -1; float b1v = -3.4e38f;
  #pragma unroll
  for (int ee = 0; ee < Edim; ee++) if (ee != e0 && logitv[ee] > b1v) { b1v = logitv[ee]; e1 = ee; }
  float texp = expf(b1v - b0v);
  float g0 = 1.f / (1.f + texp);
  float g1 = texp / (1.f + texp);
  int p0 = atomicAdd(&counts[e0], 1);
  tok_list[e0 * Ntok + p0] = t;
  int p1 = atomicAdd(&counts[e1], 1);
  tok_list[e1 * Ntok + p1] = t;
  tokslot[t] = make_int4(e0, p0, e1, p1);
  tokgate[t] = make_float2(g0, g1);
}

// ---------- offsets + compacted row worklist ----------
__global__ void offsets_kernel(const int* __restrict__ counts, int* __restrict__ offs,
                               int* __restrict__ rowmap, int* __restrict__ nrows) {
  if (threadIdx.x == 0) {
    int r = 0, nr = 0;
    for (int e = 0; e < Edim; e++) {
      offs[e] = r;
      int ne = counts[e];
      for (int tb = 0; tb < ne; tb += 128) rowmap[nr++] = (e << 16) | (tb >> 7);
      r += ne;
    }
    nrows[0] = nr;
  }
}

// ---------- fc1: h = relu(x @ W1 + b1)^2, 128x128 tile, SINGLE-buffer ----------
__global__ __launch_bounds__(256)
void fc1_kernel(const u16* __restrict__ x16, const u16* __restrict__ W1T,
                const float* __restrict__ b1, const int* __restrict__ counts,
                const int* __restrict__ offs, const int* __restrict__ tok_list,
                const int* __restrict__ rowmap, const int* __restrict__ nrows,
                u16* __restrict__ h_buf) {
  const int l = xcd_remap(blockIdx.x, MAXROWS * 24);
  const int r = l / 24;
  if (r >= nrows[0]) return;
  const int hB = l % 24;
  const int rm = rowmap[r];
  const int e = rm >> 16;
  const int tokBase = (rm & 0xffff) << 7;
  const int n_e = counts[e];
  const int hBase = hB * 128;
  __shared__ u16 As[4096];
  __shared__ u16 Bs[4096];
  __shared__ int toks[128];
  const int tid = threadIdx.x;
  if (tid < 128) {
    int s = tokBase + tid;
    toks[tid] = (s < n_e) ? tok_list[e * Ntok + s] : 0;
  }
  __syncthreads();
  const int lane = tid & 63, wv = tid >> 6;
  const int wr = wv >> 1, wc = wv & 1;
  const int sRow = lane >> 2, sSlot = lane & 3;
  const int kbOff = (sSlot ^ ((sRow >> 1) & 3)) * 8;
  const int rA0 = wv * 16 + sRow, rA1 = 64 + rA0;
  const u16* pA0 = x16 + (size_t)toks[rA0] * Cdim + kbOff;
  const u16* pA1 = x16 + (size_t)toks[rA1] * Cdim + kbOff;
  const u16* pB0 = W1T + ((size_t)e * Hdim + hBase + rA0) * Cdim + kbOff;
  const u16* pB1 = W1T + ((size_t)e * Hdim + hBase + rA1) * Cdim + kbOff;
  const int stOff = wv * 512 + lane * 8;
  const int fr = lane & 15;
  const int qsw = (((lane >> 4) ^ ((fr >> 1) & 3))) * 8;
  f32x4 acc[4][4] = {};
  for (int it = 0; it < 24; it++) {
    int k0 = it * 32;
    gld16(pA0 + k0, &As[stOff]);
    gld16(pA1 + k0, &As[2048 + stOff]);
    gld16(pB0 + k0, &Bs[stOff]);
    gld16(pB1 + k0, &Bs[2048 + stOff]);
    __syncthreads();
    short8 aF[4], bF[4];
    #pragma unroll
    for (int m = 0; m < 4; m++)
      aF[m] = *reinterpret_cast<const short8*>(&As[(wr * 64 + m * 16 + fr) * 32 + qsw]);
    #pragma unroll
    for (int n = 0; n < 4; n++)
      bF[n] = *reinterpret_cast<const short8*>(&Bs[(wc * 64 + n * 16 + fr) * 32 + qsw]);
    #pragma unroll
    for (int m = 0; m < 4; m++)
      #pragma unroll
      for (int n = 0; n < 4; n++)
        acc[m][n] = __builtin_amdgcn_mfma_f32_16x16x32_bf16(aF[m], bF[n], acc[m][n], 0, 0, 0);
    __syncthreads();
  }
  const int rq = (lane >> 4) * 4;
  float bias[4];
  #pragma unroll
  for (int n = 0; n < 4; n++) bias[n] = b1[(size_t)e * Hdim + hBase + wc * 64 + n * 16 + fr];
  const int rowB = offs[e] + tokBase;
  #pragma unroll
  for (int m = 0; m < 4; m++) {
    #pragma unroll
    for (int j = 0; j < 4; j++) {
      int rl = wr * 64 + m * 16 + rq + j;
      if (tokBase + rl < n_e) {
        size_t rb = (size_t)(rowB + rl) * Hdim + hBase + wc * 64 + fr;
        #pragma unroll
        for (int n = 0; n < 4; n++) {
          float v = fmaxf(acc[m][n][j] + bias[n], 0.f);
          h_buf[rb + n * 16] = f2bf(v * v);
        }
      }
    }
  }
}

// ---------- fc2: ybuf[kch][slot] = h @ W2T[kch] (+b2 on kch0), 128x128, split-K3 ----------
__global__ __launch_bounds__(256)
void fc2_kernel(const u16* __restrict__ h_buf, const u16* __restrict__ W2T,
                const float* __restrict__ b2, const int* __restrict__ counts,
                const int* __restrict__ offs, const int* __restrict__ rowmap,
                const int* __restrict__ nrows, u16* __restrict__ ybuf) {
  const int l = xcd_remap(blockIdx.x, MAXROWS * 18);
  const int r = l / 18;
  if (r >= nrows[0]) return;
  const int xb = l % 18;
  const int rm = rowmap[r];
  const int e = rm >> 16;
  const int tokBase = (rm & 0xffff) << 7;
  const int n_e = counts[e];
  const int kch = xb / 6;                  // 0..KS2-1
  const int cBase = (xb % 6) * 128;
  const size_t kOff = (size_t)kch * KC2;
  __shared__ u16 As[4096];
  __shared__ u16 Bs[4096];
  const int tid = threadIdx.x;
  const int lane = tid & 63, wv = tid >> 6;
  const int wr = wv >> 1, wc = wv & 1;
  const int sRow = lane >> 2, sSlot = lane & 3;
  const int kbOff = (sSlot ^ ((sRow >> 1) & 3)) * 8;
  const int rA0 = wv * 16 + sRow, rA1 = 64 + rA0;
  const int slotB = offs[e] + tokBase;
  const int s0 = min(slotB + rA0, NSLOT - 1);
  const int s1 = min(slotB + rA1, NSLOT - 1);
  const u16* pA0 = h_buf + (size_t)s0 * Hdim + kOff + kbOff;
  const u16* pA1 = h_buf + (size_t)s1 * Hdim + kOff + kbOff;
  const u16* pB0 = W2T + ((size_t)e * Cdim + cBase + rA0) * Hdim + kOff + kbOff;
  const u16* pB1 = W2T + ((size_t)e * Cdim + cBase + rA1) * Hdim + kOff + kbOff;
  const int stOff = wv * 512 + lane * 8;
  const int fr = lane & 15;
  const int qsw = (((lane >> 4) ^ ((fr >> 1) & 3))) * 8;
  f32x4 acc[4][4] = {};
  for (int it = 0; it < KC2 / 32; it++) {
    int k0 = it * 32;
    gld16(pA0 + k0, &As[stOff]);
    gld16(pA1 + k0, &As[2048 + stOff]);
    gld16(pB0 + k0, &Bs[stOff]);
    gld16(pB1 + k0, &Bs[2048 + stOff]);
    __syncthreads();
    short8 aF[4], bF[4];
    #pragma unroll
    for (int m = 0; m < 4; m++)
      aF[m] = *reinterpret_cast<const short8*>(&As[(wr * 64 + m * 16 + fr) * 32 + qsw]);
    #pragma unroll
    for (int n = 0; n < 4; n++)
      bF[n] = *reinterpret_cast<const short8*>(&Bs[(wc * 64 + n * 16 + fr) * 32 + qsw]);
    #pragma unroll
    for (int m = 0; m < 4; m++)
      #pragma unroll
      for (int n = 0; n < 4; n++)
        acc[m][n] = __builtin_amdgcn_mfma_f32_16x16x32_bf16(aF[m], bF[n], acc[m][n], 0, 0, 0);
    __syncthreads();
  }
  const int rq = (lane >> 4) * 4;
  float bias[4];
  #pragma unroll
  for (int n = 0; n < 4; n++)
    bias[n] = (kch == 0) ? b2[(size_t)e * Cdim + cBase + wc * 64 + n * 16 + fr] : 0.f;
  u16* yb = ybuf + (size_t)kch * NSLOT * Cdim;
  #pragma unroll
  for (int m = 0; m < 4; m++) {
    #pragma unroll
    for (int j = 0; j < 4; j++) {
      int rl = wr * 64 + m * 16 + rq + j;
      if (tokBase + rl < n_e) {
        u16* ob = yb + (size_t)(slotB + rl) * Cdim + cBase + wc * 64 + fr;
        #pragma unroll
        for (int n = 0; n < 4; n++)
          ob[n * 16] = f2bf(acc[m][n][j] + bias[n]);
      }
    }
  }
}

// ---------- gather ----------
__global__ __launch_bounds__(256)
void gather_kernel(const u16* __restrict__ ybuf, const int4* __restrict__ tokslot,
                   const float2* __restrict__ tokgate, const int* __restrict__ offs,
                   float* __restrict__ out) {
  const int gid = blockIdx.x * 256 + threadIdx.x;
  const int t = gid / 192;
  const int c4 = (gid - t * 192) * 4;
  int4 ts = tokslot[t];
  float2 g = tokgate[t];
  size_t s0 = (size_t)(offs[ts.x] + ts.y) * Cdim + c4;
  size_t s1 = (size_t)(offs[ts.z] + ts.w) * Cdim + c4;
  const size_t K1 = (size_t)NSLOT * Cdim;
  float acc0[4] = {}, acc1[4] = {};
  #pragma unroll
  for (int k = 0; k < KS2; k++) {
    ushort4v a = *reinterpret_cast<const ushort4v*>(ybuf + k * K1 + s0);
    ushort4v b = *reinterpret_cast<const ushort4v*>(ybuf + k * K1 + s1);
    #pragma unroll
    for (int j = 0; j < 4; j++) { acc0[j] += bf2f(a[j]); acc1[j] += bf2f(b[j]); }
  }
  float4 o;
  o.x = g.x * acc0[0] + g.y * acc1[0];
  o.y = g.x * acc0[1] + g.y * acc1[1];
  o.z = g.x * acc0[2] + g.y * acc1[2];
  o.w = g.x * acc0[3] + g.y * acc1[3];
  *reinterpret_cast<float4*>(out + (size_t)t * Cdim + c4) = o;
}

extern "C" void kernel_launch(void* const* d_in, const int* in_sizes, int n_in,
                              void* d_out, int out_size, void* d_ws, size_t ws_size,
                              hipStream_t stream) {
  const float* x        = (const float*)d_in[0];
  const float* router_w = (const float*)d_in[1];
  const float* probe_w  = (const float*)d_in[2];
  const float* emb      = (const float*)d_in[3];
  const float* fatigue  = (const float*)d_in[4];
  const float* energy   = (const float*)d_in[5];
  const float* wf1      = (const float*)d_in[6];
  const float* ws1      = (const float*)d_in[7];
  const float* hf1      = (const float*)d_in[8];
  const float* mg1      = (const float*)d_in[9];
  const float* b1       = (const float*)d_in[10];
  const float* wf2      = (const float*)d_in[11];
  const float* ws2      = (const float*)d_in[12];
  const float* hf2      = (const float*)d_in[13];
  const float* mg2      = (const float*)d_in[14];
  const float* b2       = (const float*)d_in[15];
  float* out = (float*)d_out;
  char* ws = (char*)d_ws;

  u16*    x16       = (u16*)(ws + OFF_XB);
  u16*    W1T       = (u16*)(ws + OFF_W1T);
  u16*    W2T       = (u16*)(ws + OFF_W2T);
  u16*    hbuf      = (u16*)(ws + OFF_HBUF);
  float*  xT        = (float*)(ws + OFF_XT);
  float*  part      = (float*)(ws + OFF_PART);
  u16*    ybuf      = (u16*)(ws + OFF_YB);
  int*    tok_list  = (int*)(ws + OFF_TOK);
  int*    rowmap    = (int*)(ws + OFF_RM);
  int*    nrows     = (int*)(ws + OFF_NR);
  int*    counts    = (int*)(ws + OFF_CNT);
  int*    offs      = (int*)(ws + OFF_OFFS);
  int4*   tokslot   = (int4*)(ws + OFF_TSLOT);
  float2* tokgate   = (float2*)(ws + OFF_TG);

  hipMemsetAsync(counts, 0, 64, stream);

  prep_x2_kernel<<<dim3(Cdim / 64, Ntok / 64), 256, 0, stream>>>(x, x16, xT);
  logits_part_kernel<<<dim3(Ntok / 256, NCHUNK), 256, 0, stream>>>(xT, router_w, probe_w, part);
  router_fin_kernel<<<Ntok / 256, 256, 0, stream>>>(part, emb, fatigue, energy,
                                                    counts, tok_list, tokslot, tokgate);
  prep_wt2_kernel<<<NPREP, 256, 0, stream>>>(wf1, ws1, hf1, mg1, W1T,
                                             wf2, ws2, hf2, mg2, W2T);
  offsets_kernel<<<1, 64, 0, stream>>>(counts, offs, rowmap, nrows);
  fc1_kernel<<<MAXROWS * 24, 256, 0, stream>>>(x16, W1T, b1, counts, offs, tok_list,
                                               rowmap, nrows, hbuf);
  fc2_kernel<<<MAXROWS * 18, 256, 0, stream>>>(hbuf, W2T, b2, counts, offs,
                                               rowmap, nrows, ybuf);
  gather_kernel<<<Ntok * 192 / 256, 256, 0, stream>>>(ybuf, tokslot, tokgate, offs, out);
  (void)in_sizes; (void)n_in; (void)out_size; (void)ws_size;
}

// Round 20
// 341.241 us; speedup vs baseline: 1.0916x; 1.0137x over previous
//
#include <hip/hip_runtime.h>

typedef unsigned short u16;
typedef __attribute__((ext_vector_type(8))) short short8;
typedef __attribute__((ext_vector_type(8))) unsigned short ushort8;
typedef __attribute__((ext_vector_type(4))) unsigned short ushort4v;
typedef __attribute__((ext_vector_type(4))) float f32x4;

static constexpr int Cdim = 768;
static constexpr int Hdim = 3072;
static constexpr int Edim = 8;
static constexpr int Ntok = 4096;   // B*T
static constexpr int DRc  = 24;
static constexpr int NSLOT = Ntok * 2;  // 8192
static constexpr int NCHUNK = 8;
static constexpr int CCH = Cdim / NCHUNK;  // 96
static constexpr int KS2 = 3;              // fc2 split-K factor
static constexpr int KC2 = Hdim / KS2;     // 1024
static constexpr int MAXROWS = 71;         // sum ceil(n_e/128) <= 64+7
static constexpr int NFC1 = MAXROWS * 24;  // 1704

// ---- workspace layout (bytes) ----
static constexpr size_t OFF_XB   = 0;                          // x bf16: 6,291,456
static constexpr size_t OFF_W1T  = 6291456;                    // [E][H][C] bf16: 37,748,736
static constexpr size_t OFF_W2T  = 44040192;                   // [E][C][H] bf16: 37,748,736
static constexpr size_t OFF_HBUF = 81788928;                   // 8192*3072*2 = 50,331,648
// xT/part alias hbuf (dead before fc1); ybuf aliases W1T (dead after fc1)
static constexpr size_t OFF_XT   = OFF_HBUF;                   // f32 [C][N]: 12,582,912
static constexpr size_t OFF_PART = OFF_HBUF + 12582912;        // f32 [8][33][N]: 4,325,376
static constexpr size_t OFF_YB   = OFF_W1T;                    // bf16 [3][NSLOT][C]: 37,748,736
static constexpr size_t OFF_TOK  = 132120576;                  // E*N*4 = 131,072
static constexpr size_t OFF_RM   = 132251648;                  // rowmap int[71]
static constexpr size_t OFF_NR   = 132252160;                  // nrows int[1]
static constexpr size_t OFF_CNT  = 132382720;                  // 8*4
static constexpr size_t OFF_OFFS = 132382752;                  // 8*4
static constexpr size_t OFF_TSLOT= 132382784;                  // int4 [Ntok]: 65,536
static constexpr size_t OFF_TG   = 132448320;                  // float2 [Ntok]: 32,768

__device__ __forceinline__ u16 f2bf(float f) {
  unsigned u = __builtin_bit_cast(unsigned, f);
  u += 0x7fffu + ((u >> 16) & 1u);          // round-to-nearest-even
  return (u16)(u >> 16);
}

__device__ __forceinline__ float bf2f(u16 v) {
  unsigned u = ((unsigned)v) << 16;
  return __builtin_bit_cast(float, u);
}

// async global->LDS, 16B per lane (HW: wave-uniform LDS base + lane*16)
__device__ __forceinline__ void gld16(const u16* g, u16* l) {
  __builtin_amdgcn_global_load_lds((const __attribute__((address_space(1))) unsigned int*)g,
                                   (__attribute__((address_space(3))) unsigned int*)l,
                                   16, 0, 0);
}

// bijective chunked XCD remap (m204)
__device__ __forceinline__ int xcd_remap(int p, int nwg) {
  int q = nwg >> 3, rem = nwg & 7;
  int x = p & 7, i = p >> 3;
  return (x < rem ? x * (q + 1) : rem * (q + 1) + (x - rem) * q) + i;
}

// ---------- prep W tile body: 64r x 128c, u32 column-pair LDS ----------
template<int R, int CCOL>
__device__ __forceinline__ void prep_wt_body(const float* __restrict__ wf,
                                             const float* __restrict__ wsl,
                                             const float* __restrict__ hf, float m,
                                             u16* __restrict__ outw, int e, int r0, int c0,
                                             unsigned* lds) {
  const size_t base = (size_t)e * R * CCOL;
  const int t = threadIdx.x;
  {
    const int rp = t >> 5;            // 0..7
    const int col4 = (t & 31) * 4;    // 0..124
    const int c2w = (t & 31) * 2;
    #pragma unroll
    for (int i = 0; i < 8; i++) {
      int r = i * 8 + rp;
      size_t idx = base + (size_t)(r0 + r) * CCOL + c0 + col4;
      float4 a = *(const float4*)(wf + idx);
      float4 b = *(const float4*)(wsl + idx);
      float4 h = *(const float4*)(hf + idx);
      unsigned u0 = (unsigned)f2bf(fmaf(m, b.x, a.x) + h.x)
                  | ((unsigned)f2bf(fmaf(m, b.y, a.y) + h.y) << 16);
      unsigned u1 = (unsigned)f2bf(fmaf(m, b.z, a.z) + h.z)
                  | ((unsigned)f2bf(fmaf(m, b.w, a.w) + h.w) << 16);
      lds[c2w * 65 + r] = u0;
      lds[(c2w + 1) * 65 + r] = u1;
    }
  }
  __syncthreads();
  {
    const int c2 = t >> 2;            // 0..63 (column pair)
    const int rseg = (t & 3) * 16;    // 16-row segment
    const unsigned* cp = lds + c2 * 65 + rseg;
    unsigned in4[16];
    #pragma unroll
    for (int j = 0; j < 4; j++)
      *reinterpret_cast<uint4*>(&in4[j * 4]) = *reinterpret_cast<const uint4*>(cp + j * 4);
    unsigned lo[8], hi[8];
    #pragma unroll
    for (int j = 0; j < 8; j++) {
      unsigned a = in4[2 * j], b = in4[2 * j + 1];
      lo[j] = (a & 0xffffu) | (b << 16);
      hi[j] = (a >> 16) | (b & 0xffff0000u);
    }
    size_t ob = ((size_t)e * CCOL + c0 + 2 * c2) * R + r0 + rseg;   // u16 units
    *reinterpret_cast<uint4*>(outw + ob)          = *reinterpret_cast<const uint4*>(&lo[0]);
    *reinterpret_cast<uint4*>(outw + ob + 8)      = *reinterpret_cast<const uint4*>(&lo[4]);
    *reinterpret_cast<uint4*>(outw + ob + R)      = *reinterpret_cast<const uint4*>(&hi[0]);
    *reinterpret_cast<uint4*>(outw + ob + R + 8)  = *reinterpret_cast<const uint4*>(&hi[4]);
  }
}

// ---------- fused: prep_x2 (768 blocks) + prep_wt layer1 (2304 blocks) ----------
__global__ __launch_bounds__(256)
void fused_pre1_kernel(const float* __restrict__ x, u16* __restrict__ x16,
                       float* __restrict__ xT,
                       const float* __restrict__ wf1, const float* __restrict__ ws1,
                       const float* __restrict__ hf1, const float* __restrict__ mg1,
                       u16* __restrict__ W1T) {
  __shared__ unsigned lsbuf[64 * 65];      // 16,640 B (union: float tile / u32 pairs)
  int bid = blockIdx.x;
  if (bid < 768) {
    // ---- prep_x2: x -> bf16 [N][C] and f32 transpose [C][N] ----
    float* tile = reinterpret_cast<float*>(lsbuf);    // [64][65]
    const int c0 = (bid % 12) * 64;
    const int t0 = (bid / 12) * 64;
    const int tid = threadIdx.x;
    const int row = tid >> 4, col = (tid & 15) * 4;
    #pragma unroll
    for (int i = 0; i < 4; i++) {
      int r = row + i * 16;
      size_t idx = (size_t)(t0 + r) * Cdim + c0 + col;
      float4 v = *(const float4*)(x + idx);
      tile[r * 65 + col + 0] = v.x; tile[r * 65 + col + 1] = v.y;
      tile[r * 65 + col + 2] = v.z; tile[r * 65 + col + 3] = v.w;
      ushort4v o = { f2bf(v.x), f2bf(v.y), f2bf(v.z), f2bf(v.w) };
      *reinterpret_cast<ushort4v*>(x16 + idx) = o;
    }
    __syncthreads();
    const int c = tid >> 2, tg = (tid & 3) * 16;
    #pragma unroll
    for (int q = 0; q < 4; q++) {
      float4 w;
      w.x = tile[(tg + q * 4 + 0) * 65 + c];
      w.y = tile[(tg + q * 4 + 1) * 65 + c];
      w.z = tile[(tg + q * 4 + 2) * 65 + c];
      w.w = tile[(tg + q * 4 + 3) * 65 + c];
      *reinterpret_cast<float4*>(xT + (size_t)(c0 + c) * Ntok + t0 + tg + q * 4) = w;
    }
  } else {
    // ---- prep_wt layer1: [E][C][H] -> W1T [E][H][C] ----
    bid -= 768;
    int e = bid / 288, rem = bid % 288;
    int xx = rem % 12, yy = rem / 12;
    prep_wt_body<768, 3072>(wf1, ws1, hf1, mg1[e], W1T, e, xx * 64, yy * 128, lsbuf);
  }
}

// ---------- router part 1 ----------
__global__ __launch_bounds__(256)
void logits_part_kernel(const float* __restrict__ xT, const float* __restrict__ router_w,
                        const float* __restrict__ probe_w, float* __restrict__ part) {
  const int t = blockIdx.x * 256 + threadIdx.x;
  const int cB = blockIdx.y * CCH;
  float racc[Edim] = {};
  float pacc[DRc] = {};
  float sacc = 0.f;
  for (int ci = 0; ci < CCH; ci++) {
    int c = cB + ci;
    float xv = xT[(size_t)c * Ntok + t];
    sacc += xv;
    #pragma unroll
    for (int ee = 0; ee < Edim; ee++) racc[ee] = fmaf(xv, router_w[ee * Cdim + c], racc[ee]);
    #pragma unroll
    for (int d = 0; d < DRc; d++) pacc[d] = fmaf(xv, probe_w[d * Cdim + c], pacc[d]);
  }
  float* pb = part + (size_t)blockIdx.y * 33 * Ntok + t;
  #pragma unroll
  for (int ee = 0; ee < Edim; ee++) pb[(size_t)ee * Ntok] = racc[ee];
  #pragma unroll
  for (int d = 0; d < DRc; d++) pb[(size_t)(8 + d) * Ntok] = pacc[d];
  pb[(size_t)32 * Ntok] = sacc;
}

// ---------- router part 2 ----------
__global__ __launch_bounds__(256)
void router_fin_kernel(const float* __restrict__ part, const float* __restrict__ emb,
                       const float* __restrict__ fatigue, const float* __restrict__ energy,
                       int* __restrict__ counts, int* __restrict__ tok_list,
                       int4* __restrict__ tokslot, float2* __restrict__ tokgate) {
  const int t = blockIdx.x * 256 + threadIdx.x;
  float v[33];
  #pragma unroll
  for (int o = 0; o < 33; o++) {
    float s = 0.f;
    #pragma unroll
    for (int ch = 0; ch < NCHUNK; ch++)
      s += part[((size_t)ch * 33 + o) * Ntok + t];
    v[o] = s;
  }
  const float* racc = v;
  const float* pacc = v + 8;
  float proxy = v[32] / 768.f;
  float pn2 = 0.f;
  #pragma unroll
  for (int d = 0; d < DRc; d++) pn2 += pacc[d] * pacc[d];
  float pnorm = sqrtf(pn2);
  float logitv[Edim];
  #pragma unroll
  for (int ee = 0; ee < Edim; ee++) {
    float g2 = 0.f, dote = 0.f;
    #pragma unroll
    for (int d = 0; d < DRc; d++) {
      float ev = emb[ee * DRc + d];
      g2 += ev * ev;
      dote += pacc[d] * ev;
    }
    float gain = sqrtf(g2);
    float align = dote / (fmaxf(pnorm, 1e-12f) * fmaxf(gain, 1e-12f));
    logitv[ee] = racc[ee] + 0.02f * proxy * (1.f + gain) + 0.02f * align
               + 0.1f * energy[ee] - 0.1f * fatigue[ee];
  }
  int e0 = 0; float b0v = logitv[0];
  #pragma unroll
  for (int ee = 1; ee < Edim; ee++) if (logitv[ee] > b0v) { b0v = logitv[ee]; e0 = ee; }
  int e1 = -1; float b1v = -3.4e38f;
  #pragma unroll
  for (int ee = 0; ee < Edim; ee++) if (ee != e0 && logitv[ee] > b1v) { b1v = logitv[ee]; e1 = ee; }
  float texp = expf(b1v - b0v);
  float g0 = 1.f / (1.f + texp);
  float g1 = texp / (1.f + texp);
  int p0 = atomicAdd(&counts[e0], 1);
  tok_list[e0 * Ntok + p0] = t;
  int p1 = atomicAdd(&counts[e1], 1);
  tok_list[e1 * Ntok + p1] = t;
  tokslot[t] = make_int4(e0, p0, e1, p1);
  tokgate[t] = make_float2(g0, g1);
}

// ---------- offsets + compacted row worklist ----------
__global__ void offsets_kernel(const int* __restrict__ counts, int* __restrict__ offs,
                               int* __restrict__ rowmap, int* __restrict__ nrows) {
  if (threadIdx.x == 0) {
    int r = 0, nr = 0;
    for (int e = 0; e < Edim; e++) {
      offs[e] = r;
      int ne = counts[e];
      for (int tb = 0; tb < ne; tb += 128) rowmap[nr++] = (e << 16) | (tb >> 7);
      r += ne;
    }
    nrows[0] = nr;
  }
}

// ---------- fused: fc1 (1704 blocks) + prep_wt layer2 (2304 blocks) ----------
// fc1 reads W1T only; prep_L2 writes W2T only -> data-independent, co-scheduled.
__global__ __launch_bounds__(256)
void fused_fc1p2_kernel(const u16* __restrict__ x16, const u16* __restrict__ W1T,
                        const float* __restrict__ b1, const int* __restrict__ counts,
                        const int* __restrict__ offs, const int* __restrict__ tok_list,
                        const int* __restrict__ rowmap, const int* __restrict__ nrows,
                        u16* __restrict__ h_buf,
                        const float* __restrict__ wf2, const float* __restrict__ ws2,
                        const float* __restrict__ hf2, const float* __restrict__ mg2,
                        u16* __restrict__ W2T) {
  __shared__ unsigned smem4[4224];          // 16,896 B union
  if (blockIdx.x >= NFC1) {
    // ---- prep_wt layer2: [E][H][C] -> W2T [E][C][H] ----
    int bid = blockIdx.x - NFC1;
    int e = bid / 288, rem = bid % 288;
    int xx = rem % 48, yy = rem / 48;
    prep_wt_body<3072, 768>(wf2, ws2, hf2, mg2[e], W2T, e, xx * 64, yy * 128, smem4);
    return;
  }
  // ---- fc1: h = relu(x @ W1 + b1)^2, 128x128 tile, single-buffer ----
  u16* As = reinterpret_cast<u16*>(smem4);          // 4096 u16
  u16* Bs = As + 4096;                              // 4096 u16
  int* toks = reinterpret_cast<int*>(As + 8192);    // 128 int
  const int l = xcd_remap(blockIdx.x, NFC1);
  const int r = l / 24;
  if (r >= nrows[0]) return;
  const int hB = l % 24;
  const int rm = rowmap[r];
  const int e = rm >> 16;
  const int tokBase = (rm & 0xffff) << 7;
  const int n_e = counts[e];
  const int hBase = hB * 128;
  const int tid = threadIdx.x;
  if (tid < 128) {
    int s = tokBase + tid;
    toks[tid] = (s < n_e) ? tok_list[e * Ntok + s] : 0;
  }
  __syncthreads();
  const int lane = tid & 63, wv = tid >> 6;
  const int wr = wv >> 1, wc = wv & 1;
  const int sRow = lane >> 2, sSlot = lane & 3;
  const int kbOff = (sSlot ^ ((sRow >> 1) & 3)) * 8;
  const int rA0 = wv * 16 + sRow, rA1 = 64 + rA0;
  const u16* pA0 = x16 + (size_t)toks[rA0] * Cdim + kbOff;
  const u16* pA1 = x16 + (size_t)toks[rA1] * Cdim + kbOff;
  const u16* pB0 = W1T + ((size_t)e * Hdim + hBase + rA0) * Cdim + kbOff;
  const u16* pB1 = W1T + ((size_t)e * Hdim + hBase + rA1) * Cdim + kbOff;
  const int stOff = wv * 512 + lane * 8;
  const int fr = lane & 15;
  const int qsw = (((lane >> 4) ^ ((fr >> 1) & 3))) * 8;
  f32x4 acc[4][4] = {};
  for (int it = 0; it < 24; it++) {
    int k0 = it * 32;
    gld16(pA0 + k0, As + stOff);
    gld16(pA1 + k0, As + 2048 + stOff);
    gld16(pB0 + k0, Bs + stOff);
    gld16(pB1 + k0, Bs + 2048 + stOff);
    __syncthreads();
    short8 aF[4], bF[4];
    #pragma unroll
    for (int m = 0; m < 4; m++)
      aF[m] = *reinterpret_cast<const short8*>(As + (wr * 64 + m * 16 + fr) * 32 + qsw);
    #pragma unroll
    for (int n = 0; n < 4; n++)
      bF[n] = *reinterpret_cast<const short8*>(Bs + (wc * 64 + n * 16 + fr) * 32 + qsw);
    #pragma unroll
    for (int m = 0; m < 4; m++)
      #pragma unroll
      for (int n = 0; n < 4; n++)
        acc[m][n] = __builtin_amdgcn_mfma_f32_16x16x32_bf16(aF[m], bF[n], acc[m][n], 0, 0, 0);
    __syncthreads();
  }
  const int rq = (lane >> 4) * 4;
  float bias[4];
  #pragma unroll
  for (int n = 0; n < 4; n++) bias[n] = b1[(size_t)e * Hdim + hBase + wc * 64 + n * 16 + fr];
  const int rowB = offs[e] + tokBase;
  #pragma unroll
  for (int m = 0; m < 4; m++) {
    #pragma unroll
    for (int j = 0; j < 4; j++) {
      int rl = wr * 64 + m * 16 + rq + j;
      if (tokBase + rl < n_e) {
        size_t rb = (size_t)(rowB + rl) * Hdim + hBase + wc * 64 + fr;
        #pragma unroll
        for (int n = 0; n < 4; n++) {
          float v = fmaxf(acc[m][n][j] + bias[n], 0.f);
          h_buf[rb + n * 16] = f2bf(v * v);
        }
      }
    }
  }
}

// ---------- fc2: ybuf[kch][slot] = h @ W2T[kch] (+b2 on kch0), 128x128, split-K3 ----------
__global__ __launch_bounds__(256)
void fc2_kernel(const u16* __restrict__ h_buf, const u16* __restrict__ W2T,
                const float* __restrict__ b2, const int* __restrict__ counts,
                const int* __restrict__ offs, const int* __restrict__ rowmap,
                const int* __restrict__ nrows, u16* __restrict__ ybuf) {
  const int l = xcd_remap(blockIdx.x, MAXROWS * 18);
  const int r = l / 18;
  if (r >= nrows[0]) return;
  const int xb = l % 18;
  const int rm = rowmap[r];
  const int e = rm >> 16;
  const int tokBase = (rm & 0xffff) << 7;
  const int n_e = counts[e];
  const int kch = xb / 6;                  // 0..KS2-1
  const int cBase = (xb % 6) * 128;
  const size_t kOff = (size_t)kch * KC2;
  __shared__ u16 As[4096];
  __shared__ u16 Bs[4096];
  const int tid = threadIdx.x;
  const int lane = tid & 63, wv = tid >> 6;
  const int wr = wv >> 1, wc = wv & 1;
  const int sRow = lane >> 2, sSlot = lane & 3;
  const int kbOff = (sSlot ^ ((sRow >> 1) & 3)) * 8;
  const int rA0 = wv * 16 + sRow, rA1 = 64 + rA0;
  const int slotB = offs[e] + tokBase;
  const int s0 = min(slotB + rA0, NSLOT - 1);
  const int s1 = min(slotB + rA1, NSLOT - 1);
  const u16* pA0 = h_buf + (size_t)s0 * Hdim + kOff + kbOff;
  const u16* pA1 = h_buf + (size_t)s1 * Hdim + kOff + kbOff;
  const u16* pB0 = W2T + ((size_t)e * Cdim + cBase + rA0) * Hdim + kOff + kbOff;
  const u16* pB1 = W2T + ((size_t)e * Cdim + cBase + rA1) * Hdim + kOff + kbOff;
  const int stOff = wv * 512 + lane * 8;
  const int fr = lane & 15;
  const int qsw = (((lane >> 4) ^ ((fr >> 1) & 3))) * 8;
  f32x4 acc[4][4] = {};
  for (int it = 0; it < KC2 / 32; it++) {
    int k0 = it * 32;
    gld16(pA0 + k0, &As[stOff]);
    gld16(pA1 + k0, &As[2048 + stOff]);
    gld16(pB0 + k0, &Bs[stOff]);
    gld16(pB1 + k0, &Bs[2048 + stOff]);
    __syncthreads();
    short8 aF[4], bF[4];
    #pragma unroll
    for (int m = 0; m < 4; m++)
      aF[m] = *reinterpret_cast<const short8*>(&As[(wr * 64 + m * 16 + fr) * 32 + qsw]);
    #pragma unroll
    for (int n = 0; n < 4; n++)
      bF[n] = *reinterpret_cast<const short8*>(&Bs[(wc * 64 + n * 16 + fr) * 32 + qsw]);
    #pragma unroll
    for (int m = 0; m < 4; m++)
      #pragma unroll
      for (int n = 0; n < 4; n++)
        acc[m][n] = __builtin_amdgcn_mfma_f32_16x16x32_bf16(aF[m], bF[n], acc[m][n], 0, 0, 0);
    __syncthreads();
  }
  const int rq = (lane >> 4) * 4;
  float bias[4];
  #pragma unroll
  for (int n = 0; n < 4; n++)
    bias[n] = (kch == 0) ? b2[(size_t)e * Cdim + cBase + wc * 64 + n * 16 + fr] : 0.f;
  u16* yb = ybuf + (size_t)kch * NSLOT * Cdim;
  #pragma unroll
  for (int m = 0; m < 4; m++) {
    #pragma unroll
    for (int j = 0; j < 4; j++) {
      int rl = wr * 64 + m * 16 + rq + j;
      if (tokBase + rl < n_e) {
        u16* ob = yb + (size_t)(slotB + rl) * Cdim + cBase + wc * 64 + fr;
        #pragma unroll
        for (int n = 0; n < 4; n++)
          ob[n * 16] = f2bf(acc[m][n][j] + bias[n]);
      }
    }
  }
}

// ---------- gather ----------
__global__ __launch_bounds__(256)
void gather_kernel(const u16* __restrict__ ybuf, const int4* __restrict__ tokslot,
                   const float2* __restrict__ tokgate, const int* __restrict__ offs,
                   float* __restrict__ out) {
  const int gid = blockIdx.x * 256 + threadIdx.x;
  const int t = gid / 192;
  const int c4 = (gid - t * 192) * 4;
  int4 ts = tokslot[t];
  float2 g = tokgate[t];
  size_t s0 = (size_t)(offs[ts.x] + ts.y) * Cdim + c4;
  size_t s1 = (size_t)(offs[ts.z] + ts.w) * Cdim + c4;
  const size_t K1 = (size_t)NSLOT * Cdim;
  float acc0[4] = {}, acc1[4] = {};
  #pragma unroll
  for (int k = 0; k < KS2; k++) {
    ushort4v a = *reinterpret_cast<const ushort4v*>(ybuf + k * K1 + s0);
    ushort4v b = *reinterpret_cast<const ushort4v*>(ybuf + k * K1 + s1);
    #pragma unroll
    for (int j = 0; j < 4; j++) { acc0[j] += bf2f(a[j]); acc1[j] += bf2f(b[j]); }
  }
  float4 o;
  o.x = g.x * acc0[0] + g.y * acc1[0];
  o.y = g.x * acc0[1] + g.y * acc1[1];
  o.z = g.x * acc0[2] + g.y * acc1[2];
  o.w = g.x * acc0[3] + g.y * acc1[3];
  *reinterpret_cast<float4*>(out + (size_t)t * Cdim + c4) = o;
}

extern "C" void kernel_launch(void* const* d_in, const int* in_sizes, int n_in,
                              void* d_out, int out_size, void* d_ws, size_t ws_size,
                              hipStream_t stream) {
  const float* x        = (const float*)d_in[0];
  const float* router_w = (const float*)d_in[1];
  const float* probe_w  = (const float*)d_in[2];
  const float* emb      = (const float*)d_in[3];
  const float* fatigue  = (const float*)d_in[4];
  const float* energy   = (const float*)d_in[5];
  const float* wf1      = (const float*)d_in[6];
  const float* ws1      = (const float*)d_in[7];
  const float* hf1      = (const float*)d_in[8];
  const float* mg1      = (const float*)d_in[9];
  const float* b1       = (const float*)d_in[10];
  const float* wf2      = (const float*)d_in[11];
  const float* ws2      = (const float*)d_in[12];
  const float* hf2      = (const float*)d_in[13];
  const float* mg2      = (const float*)d_in[14];
  const float* b2       = (const float*)d_in[15];
  float* out = (float*)d_out;
  char* ws = (char*)d_ws;

  u16*    x16       = (u16*)(ws + OFF_XB);
  u16*    W1T       = (u16*)(ws + OFF_W1T);
  u16*    W2T       = (u16*)(ws + OFF_W2T);
  u16*    hbuf      = (u16*)(ws + OFF_HBUF);
  float*  xT        = (float*)(ws + OFF_XT);
  float*  part      = (float*)(ws + OFF_PART);
  u16*    ybuf      = (u16*)(ws + OFF_YB);
  int*    tok_list  = (int*)(ws + OFF_TOK);
  int*    rowmap    = (int*)(ws + OFF_RM);
  int*    nrows     = (int*)(ws + OFF_NR);
  int*    counts    = (int*)(ws + OFF_CNT);
  int*    offs      = (int*)(ws + OFF_OFFS);
  int4*   tokslot   = (int4*)(ws + OFF_TSLOT);
  float2* tokgate   = (float2*)(ws + OFF_TG);

  hipMemsetAsync(counts, 0, 64, stream);

  fused_pre1_kernel<<<768 + 2304, 256, 0, stream>>>(x, x16, xT,
                                                    wf1, ws1, hf1, mg1, W1T);
  logits_part_kernel<<<dim3(Ntok / 256, NCHUNK), 256, 0, stream>>>(xT, router_w, probe_w, part);
  router_fin_kernel<<<Ntok / 256, 256, 0, stream>>>(part, emb, fatigue, energy,
                                                    counts, tok_list, tokslot, tokgate);
  offsets_kernel<<<1, 64, 0, stream>>>(counts, offs, rowmap, nrows);
  fused_fc1p2_kernel<<<NFC1 + 2304, 256, 0, stream>>>(x16, W1T, b1, counts, offs, tok_list,
                                                      rowmap, nrows, hbuf,
                                                      wf2, ws2, hf2, mg2, W2T);
  fc2_kernel<<<MAXROWS * 18, 256, 0, stream>>>(hbuf, W2T, b2, counts, offs,
                                               rowmap, nrows, ybuf);
  gather_kernel<<<Ntok * 192 / 256, 256, 0, stream>>>(ybuf, tokslot, tokgate, offs, out);
  (void)in_sizes; (void)n_in; (void)out_size; (void)ws_size;
}

// Round 21
// 339.588 us; speedup vs baseline: 1.0969x; 1.0049x over previous
//
#include <hip/hip_runtime.h>

typedef unsigned short u16;
typedef __attribute__((ext_vector_type(8))) short short8;
typedef __attribute__((ext_vector_type(8))) unsigned short ushort8;
typedef __attribute__((ext_vector_type(4))) unsigned short ushort4v;
typedef __attribute__((ext_vector_type(4))) float f32x4;

static constexpr int Cdim = 768;
static constexpr int Hdim = 3072;
static constexpr int Edim = 8;
static constexpr int Ntok = 4096;   // B*T
static constexpr int DRc  = 24;
static constexpr int NSLOT = Ntok * 2;  // 8192
static constexpr int NCHUNK = 8;
static constexpr int CCH = Cdim / NCHUNK;  // 96
static constexpr int KS2 = 3;              // fc2 split-K factor
static constexpr int KC2 = Hdim / KS2;     // 1024
static constexpr int MAXROWS = 71;         // sum ceil(n_e/128) <= 64+7
static constexpr int NFC1 = MAXROWS * 24;  // 1704 = 8*213
static constexpr int FCX = NFC1 / 8;       // 213 fc1 blocks per XCD
static constexpr int PRX = 2304 / 8;       // 288 prep blocks per XCD
static constexpr int SLX = FCX + PRX;      // 501 slots per XCD

// ---- workspace layout (bytes) ----
static constexpr size_t OFF_XB   = 0;                          // x bf16: 6,291,456
static constexpr size_t OFF_W1T  = 6291456;                    // [E][H][C] bf16: 37,748,736
static constexpr size_t OFF_W2T  = 44040192;                   // [E][C][H] bf16: 37,748,736
static constexpr size_t OFF_HBUF = 81788928;                   // 8192*3072*2 = 50,331,648
// xT/part alias hbuf (dead before fc1); ybuf aliases W1T (dead after fc1)
static constexpr size_t OFF_XT   = OFF_HBUF;                   // f32 [C][N]: 12,582,912
static constexpr size_t OFF_PART = OFF_HBUF + 12582912;        // f32 [8][33][N]: 4,325,376
static constexpr size_t OFF_YB   = OFF_W1T;                    // bf16 [3][NSLOT][C]: 37,748,736
static constexpr size_t OFF_TOK  = 132120576;                  // E*N*4 = 131,072
static constexpr size_t OFF_RM   = 132251648;                  // rowmap int[71]
static constexpr size_t OFF_NR   = 132252160;                  // nrows int[1]
static constexpr size_t OFF_CNT  = 132382720;                  // 8*4
static constexpr size_t OFF_OFFS = 132382752;                  // 8*4
static constexpr size_t OFF_TSLOT= 132382784;                  // int4 [Ntok]: 65,536
static constexpr size_t OFF_TG   = 132448320;                  // float2 [Ntok]: 32,768

__device__ __forceinline__ u16 f2bf(float f) {
  unsigned u = __builtin_bit_cast(unsigned, f);
  u += 0x7fffu + ((u >> 16) & 1u);          // round-to-nearest-even
  return (u16)(u >> 16);
}

__device__ __forceinline__ float bf2f(u16 v) {
  unsigned u = ((unsigned)v) << 16;
  return __builtin_bit_cast(float, u);
}

// async global->LDS, 16B per lane (HW: wave-uniform LDS base + lane*16)
__device__ __forceinline__ void gld16(const u16* g, u16* l) {
  __builtin_amdgcn_global_load_lds((const __attribute__((address_space(1))) unsigned int*)g,
                                   (__attribute__((address_space(3))) unsigned int*)l,
                                   16, 0, 0);
}

// bijective chunked XCD remap (m204)
__device__ __forceinline__ int xcd_remap(int p, int nwg) {
  int q = nwg >> 3, rem = nwg & 7;
  int x = p & 7, i = p >> 3;
  return (x < rem ? x * (q + 1) : rem * (q + 1) + (x - rem) * q) + i;
}

// ---------- prep W tile body: 64r x 128c, u32 column-pair LDS ----------
template<int R, int CCOL>
__device__ __forceinline__ void prep_wt_body(const float* __restrict__ wf,
                                             const float* __restrict__ wsl,
                                             const float* __restrict__ hf, float m,
                                             u16* __restrict__ outw, int e, int r0, int c0,
                                             unsigned* lds) {
  const size_t base = (size_t)e * R * CCOL;
  const int t = threadIdx.x;
  {
    const int rp = t >> 5;            // 0..7
    const int col4 = (t & 31) * 4;    // 0..124
    const int c2w = (t & 31) * 2;
    #pragma unroll
    for (int i = 0; i < 8; i++) {
      int r = i * 8 + rp;
      size_t idx = base + (size_t)(r0 + r) * CCOL + c0 + col4;
      float4 a = *(const float4*)(wf + idx);
      float4 b = *(const float4*)(wsl + idx);
      float4 h = *(const float4*)(hf + idx);
      unsigned u0 = (unsigned)f2bf(fmaf(m, b.x, a.x) + h.x)
                  | ((unsigned)f2bf(fmaf(m, b.y, a.y) + h.y) << 16);
      unsigned u1 = (unsigned)f2bf(fmaf(m, b.z, a.z) + h.z)
                  | ((unsigned)f2bf(fmaf(m, b.w, a.w) + h.w) << 16);
      lds[c2w * 65 + r] = u0;
      lds[(c2w + 1) * 65 + r] = u1;
    }
  }
  __syncthreads();
  {
    const int c2 = t >> 2;            // 0..63 (column pair)
    const int rseg = (t & 3) * 16;    // 16-row segment
    const unsigned* cp = lds + c2 * 65 + rseg;
    unsigned in4[16];
    #pragma unroll
    for (int j = 0; j < 4; j++)
      *reinterpret_cast<uint4*>(&in4[j * 4]) = *reinterpret_cast<const uint4*>(cp + j * 4);
    unsigned lo[8], hi[8];
    #pragma unroll
    for (int j = 0; j < 8; j++) {
      unsigned a = in4[2 * j], b = in4[2 * j + 1];
      lo[j] = (a & 0xffffu) | (b << 16);
      hi[j] = (a >> 16) | (b & 0xffff0000u);
    }
    size_t ob = ((size_t)e * CCOL + c0 + 2 * c2) * R + r0 + rseg;   // u16 units
    *reinterpret_cast<uint4*>(outw + ob)          = *reinterpret_cast<const uint4*>(&lo[0]);
    *reinterpret_cast<uint4*>(outw + ob + 8)      = *reinterpret_cast<const uint4*>(&lo[4]);
    *reinterpret_cast<uint4*>(outw + ob + R)      = *reinterpret_cast<const uint4*>(&hi[0]);
    *reinterpret_cast<uint4*>(outw + ob + R + 8)  = *reinterpret_cast<const uint4*>(&hi[4]);
  }
}

// ---------- fused: prep_x2 (768 blocks) + prep_wt layer1 (2304 blocks) ----------
__global__ __launch_bounds__(256)
void fused_pre1_kernel(const float* __restrict__ x, u16* __restrict__ x16,
                       float* __restrict__ xT,
                       const float* __restrict__ wf1, const float* __restrict__ ws1,
                       const float* __restrict__ hf1, const float* __restrict__ mg1,
                       u16* __restrict__ W1T) {
  __shared__ unsigned lsbuf[64 * 65];      // 16,640 B (union: float tile / u32 pairs)
  int bid = blockIdx.x;
  if (bid < 768) {
    // ---- prep_x2: x -> bf16 [N][C] and f32 transpose [C][N] ----
    float* tile = reinterpret_cast<float*>(lsbuf);    // [64][65]
    const int c0 = (bid % 12) * 64;
    const int t0 = (bid / 12) * 64;
    const int tid = threadIdx.x;
    const int row = tid >> 4, col = (tid & 15) * 4;
    #pragma unroll
    for (int i = 0; i < 4; i++) {
      int r = row + i * 16;
      size_t idx = (size_t)(t0 + r) * Cdim + c0 + col;
      float4 v = *(const float4*)(x + idx);
      tile[r * 65 + col + 0] = v.x; tile[r * 65 + col + 1] = v.y;
      tile[r * 65 + col + 2] = v.z; tile[r * 65 + col + 3] = v.w;
      ushort4v o = { f2bf(v.x), f2bf(v.y), f2bf(v.z), f2bf(v.w) };
      *reinterpret_cast<ushort4v*>(x16 + idx) = o;
    }
    __syncthreads();
    const int c = tid >> 2, tg = (tid & 3) * 16;
    #pragma unroll
    for (int q = 0; q < 4; q++) {
      float4 w;
      w.x = tile[(tg + q * 4 + 0) * 65 + c];
      w.y = tile[(tg + q * 4 + 1) * 65 + c];
      w.z = tile[(tg + q * 4 + 2) * 65 + c];
      w.w = tile[(tg + q * 4 + 3) * 65 + c];
      *reinterpret_cast<float4*>(xT + (size_t)(c0 + c) * Ntok + t0 + tg + q * 4) = w;
    }
  } else {
    // ---- prep_wt layer1: [E][C][H] -> W1T [E][H][C] ----
    bid -= 768;
    int e = bid / 288, rem = bid % 288;
    int xx = rem % 12, yy = rem / 12;
    prep_wt_body<768, 3072>(wf1, ws1, hf1, mg1[e], W1T, e, xx * 64, yy * 128, lsbuf);
  }
}

// ---------- router part 1 ----------
__global__ __launch_bounds__(256)
void logits_part_kernel(const float* __restrict__ xT, const float* __restrict__ router_w,
                        const float* __restrict__ probe_w, float* __restrict__ part) {
  const int t = blockIdx.x * 256 + threadIdx.x;
  const int cB = blockIdx.y * CCH;
  float racc[Edim] = {};
  float pacc[DRc] = {};
  float sacc = 0.f;
  for (int ci = 0; ci < CCH; ci++) {
    int c = cB + ci;
    float xv = xT[(size_t)c * Ntok + t];
    sacc += xv;
    #pragma unroll
    for (int ee = 0; ee < Edim; ee++) racc[ee] = fmaf(xv, router_w[ee * Cdim + c], racc[ee]);
    #pragma unroll
    for (int d = 0; d < DRc; d++) pacc[d] = fmaf(xv, probe_w[d * Cdim + c], pacc[d]);
  }
  float* pb = part + (size_t)blockIdx.y * 33 * Ntok + t;
  #pragma unroll
  for (int ee = 0; ee < Edim; ee++) pb[(size_t)ee * Ntok] = racc[ee];
  #pragma unroll
  for (int d = 0; d < DRc; d++) pb[(size_t)(8 + d) * Ntok] = pacc[d];
  pb[(size_t)32 * Ntok] = sacc;
}

// ---------- router part 2 ----------
__global__ __launch_bounds__(256)
void router_fin_kernel(const float* __restrict__ part, const float* __restrict__ emb,
                       const float* __restrict__ fatigue, const float* __restrict__ energy,
                       int* __restrict__ counts, int* __restrict__ tok_list,
                       int4* __restrict__ tokslot, float2* __restrict__ tokgate) {
  const int t = blockIdx.x * 256 + threadIdx.x;
  float v[33];
  #pragma unroll
  for (int o = 0; o < 33; o++) {
    float s = 0.f;
    #pragma unroll
    for (int ch = 0; ch < NCHUNK; ch++)
      s += part[((size_t)ch * 33 + o) * Ntok + t];
    v[o] = s;
  }
  const float* racc = v;
  const float* pacc = v + 8;
  float proxy = v[32] / 768.f;
  float pn2 = 0.f;
  #pragma unroll
  for (int d = 0; d < DRc; d++) pn2 += pacc[d] * pacc[d];
  float pnorm = sqrtf(pn2);
  float logitv[Edim];
  #pragma unroll
  for (int ee = 0; ee < Edim; ee++) {
    float g2 = 0.f, dote = 0.f;
    #pragma unroll
    for (int d = 0; d < DRc; d++) {
      float ev = emb[ee * DRc + d];
      g2 += ev * ev;
      dote += pacc[d] * ev;
    }
    float gain = sqrtf(g2);
    float align = dote / (fmaxf(pnorm, 1e-12f) * fmaxf(gain, 1e-12f));
    logitv[ee] = racc[ee] + 0.02f * proxy * (1.f + gain) + 0.02f * align
               + 0.1f * energy[ee] - 0.1f * fatigue[ee];
  }
  int e0 = 0; float b0v = logitv[0];
  #pragma unroll
  for (int ee = 1; ee < Edim; ee++) if (logitv[ee] > b0v) { b0v = logitv[ee]; e0 = ee; }
  int e1 = -1; float b1v = -3.4e38f;
  #pragma unroll
  for (int ee = 0; ee < Edim; ee++) if (ee != e0 && logitv[ee] > b1v) { b1v = logitv[ee]; e1 = ee; }
  float texp = expf(b1v - b0v);
  float g0 = 1.f / (1.f + texp);
  float g1 = texp / (1.f + texp);
  int p0 = atomicAdd(&counts[e0], 1);
  tok_list[e0 * Ntok + p0] = t;
  int p1 = atomicAdd(&counts[e1], 1);
  tok_list[e1 * Ntok + p1] = t;
  tokslot[t] = make_int4(e0, p0, e1, p1);
  tokgate[t] = make_float2(g0, g1);
}

// ---------- offsets + compacted row worklist ----------
__global__ void offsets_kernel(const int* __restrict__ counts, int* __restrict__ offs,
                               int* __restrict__ rowmap, int* __restrict__ nrows) {
  if (threadIdx.x == 0) {
    int r = 0, nr = 0;
    for (int e = 0; e < Edim; e++) {
      offs[e] = r;
      int ne = counts[e];
      for (int tb = 0; tb < ne; tb += 128) rowmap[nr++] = (e << 16) | (tb >> 7);
      r += ne;
    }
    nrows[0] = nr;
  }
}

// ---------- fused: fc1 + prep_wt layer2, per-XCD Bresenham interleave ----------
// XCD x = p&7 owns slots q = p>>3 in [0,501): 213 fc1 (contiguous logical
// chunk x*213..) + 288 prep_L2 (logical chunk x*288..), temporally mixed.
__global__ __launch_bounds__(256)
void fused_fc1p2_kernel(const u16* __restrict__ x16, const u16* __restrict__ W1T,
                        const float* __restrict__ b1, const int* __restrict__ counts,
                        const int* __restrict__ offs, const int* __restrict__ tok_list,
                        const int* __restrict__ rowmap, const int* __restrict__ nrows,
                        u16* __restrict__ h_buf,
                        const float* __restrict__ wf2, const float* __restrict__ ws2,
                        const float* __restrict__ hf2, const float* __restrict__ mg2,
                        u16* __restrict__ W2T) {
  __shared__ unsigned smem4[4224];          // 16,896 B union
  const int p = blockIdx.x;
  const int xcd = p & 7, q = p >> 3;        // slot within XCD
  const int j = (q * FCX) / SLX;            // fc1 count before slot q (Bresenham)
  const bool isFc1 = ((q + 1) * FCX) / SLX > j;
  if (!isFc1) {
    // ---- prep_wt layer2: [E][H][C] -> W2T [E][C][H] ----
    int bid = xcd * PRX + (q - j);          // logical prep id, XCD-chunked
    int e = bid / 288, rem = bid % 288;
    int xx = rem % 48, yy = rem / 48;
    prep_wt_body<3072, 768>(wf2, ws2, hf2, mg2[e], W2T, e, xx * 64, yy * 128, smem4);
    return;
  }
  // ---- fc1: h = relu(x @ W1 + b1)^2, 128x128 tile, single-buffer ----
  u16* As = reinterpret_cast<u16*>(smem4);          // 4096 u16
  u16* Bs = As + 4096;                              // 4096 u16
  int* toks = reinterpret_cast<int*>(As + 8192);    // 128 int
  const int l = xcd * FCX + j;              // logical fc1 id, XCD-chunked
  const int r = l / 24;
  if (r >= nrows[0]) return;
  const int hB = l % 24;
  const int rm = rowmap[r];
  const int e = rm >> 16;
  const int tokBase = (rm & 0xffff) << 7;
  const int n_e = counts[e];
  const int hBase = hB * 128;
  const int tid = threadIdx.x;
  if (tid < 128) {
    int s = tokBase + tid;
    toks[tid] = (s < n_e) ? tok_list[e * Ntok + s] : 0;
  }
  __syncthreads();
  const int lane = tid & 63, wv = tid >> 6;
  const int wr = wv >> 1, wc = wv & 1;
  const int sRow = lane >> 2, sSlot = lane & 3;
  const int kbOff = (sSlot ^ ((sRow >> 1) & 3)) * 8;
  const int rA0 = wv * 16 + sRow, rA1 = 64 + rA0;
  const u16* pA0 = x16 + (size_t)toks[rA0] * Cdim + kbOff;
  const u16* pA1 = x16 + (size_t)toks[rA1] * Cdim + kbOff;
  const u16* pB0 = W1T + ((size_t)e * Hdim + hBase + rA0) * Cdim + kbOff;
  const u16* pB1 = W1T + ((size_t)e * Hdim + hBase + rA1) * Cdim + kbOff;
  const int stOff = wv * 512 + lane * 8;
  const int fr = lane & 15;
  const int qsw = (((lane >> 4) ^ ((fr >> 1) & 3))) * 8;
  f32x4 acc[4][4] = {};
  for (int it = 0; it < 24; it++) {
    int k0 = it * 32;
    gld16(pA0 + k0, As + stOff);
    gld16(pA1 + k0, As + 2048 + stOff);
    gld16(pB0 + k0, Bs + stOff);
    gld16(pB1 + k0, Bs + 2048 + stOff);
    __syncthreads();
    short8 aF[4], bF[4];
    #pragma unroll
    for (int m = 0; m < 4; m++)
      aF[m] = *reinterpret_cast<const short8*>(As + (wr * 64 + m * 16 + fr) * 32 + qsw);
    #pragma unroll
    for (int n = 0; n < 4; n++)
      bF[n] = *reinterpret_cast<const short8*>(Bs + (wc * 64 + n * 16 + fr) * 32 + qsw);
    #pragma unroll
    for (int m = 0; m < 4; m++)
      #pragma unroll
      for (int n = 0; n < 4; n++)
        acc[m][n] = __builtin_amdgcn_mfma_f32_16x16x32_bf16(aF[m], bF[n], acc[m][n], 0, 0, 0);
    __syncthreads();
  }
  const int rq = (lane >> 4) * 4;
  float bias[4];
  #pragma unroll
  for (int n = 0; n < 4; n++) bias[n] = b1[(size_t)e * Hdim + hBase + wc * 64 + n * 16 + fr];
  const int rowB = offs[e] + tokBase;
  #pragma unroll
  for (int m = 0; m < 4; m++) {
    #pragma unroll
    for (int j2 = 0; j2 < 4; j2++) {
      int rl = wr * 64 + m * 16 + rq + j2;
      if (tokBase + rl < n_e) {
        size_t rb = (size_t)(rowB + rl) * Hdim + hBase + wc * 64 + fr;
        #pragma unroll
        for (int n = 0; n < 4; n++) {
          float v = fmaxf(acc[m][n][j2] + bias[n], 0.f);
          h_buf[rb + n * 16] = f2bf(v * v);
        }
      }
    }
  }
}

// ---------- fc2: ybuf[kch][slot] = h @ W2T[kch] (+b2 on kch0), 128x128, split-K3 ----------
__global__ __launch_bounds__(256)
void fc2_kernel(const u16* __restrict__ h_buf, const u16* __restrict__ W2T,
                const float* __restrict__ b2, const int* __restrict__ counts,
                const int* __restrict__ offs, const int* __restrict__ rowmap,
                const int* __restrict__ nrows, u16* __restrict__ ybuf) {
  const int l = xcd_remap(blockIdx.x, MAXROWS * 18);
  const int r = l / 18;
  if (r >= nrows[0]) return;
  const int xb = l % 18;
  const int rm = rowmap[r];
  const int e = rm >> 16;
  const int tokBase = (rm & 0xffff) << 7;
  const int n_e = counts[e];
  const int kch = xb / 6;                  // 0..KS2-1
  const int cBase = (xb % 6) * 128;
  const size_t kOff = (size_t)kch * KC2;
  __shared__ u16 As[4096];
  __shared__ u16 Bs[4096];
  const int tid = threadIdx.x;
  const int lane = tid & 63, wv = tid >> 6;
  const int wr = wv >> 1, wc = wv & 1;
  const int sRow = lane >> 2, sSlot = lane & 3;
  const int kbOff = (sSlot ^ ((sRow >> 1) & 3)) * 8;
  const int rA0 = wv * 16 + sRow, rA1 = 64 + rA0;
  const int slotB = offs[e] + tokBase;
  const int s0 = min(slotB + rA0, NSLOT - 1);
  const int s1 = min(slotB + rA1, NSLOT - 1);
  const u16* pA0 = h_buf + (size_t)s0 * Hdim + kOff + kbOff;
  const u16* pA1 = h_buf + (size_t)s1 * Hdim + kOff + kbOff;
  const u16* pB0 = W2T + ((size_t)e * Cdim + cBase + rA0) * Hdim + kOff + kbOff;
  const u16* pB1 = W2T + ((size_t)e * Cdim + cBase + rA1) * Hdim + kOff + kbOff;
  const int stOff = wv * 512 + lane * 8;
  const int fr = lane & 15;
  const int qsw = (((lane >> 4) ^ ((fr >> 1) & 3))) * 8;
  f32x4 acc[4][4] = {};
  for (int it = 0; it < KC2 / 32; it++) {
    int k0 = it * 32;
    gld16(pA0 + k0, &As[stOff]);
    gld16(pA1 + k0, &As[2048 + stOff]);
    gld16(pB0 + k0, &Bs[stOff]);
    gld16(pB1 + k0, &Bs[2048 + stOff]);
    __syncthreads();
    short8 aF[4], bF[4];
    #pragma unroll
    for (int m = 0; m < 4; m++)
      aF[m] = *reinterpret_cast<const short8*>(&As[(wr * 64 + m * 16 + fr) * 32 + qsw]);
    #pragma unroll
    for (int n = 0; n < 4; n++)
      bF[n] = *reinterpret_cast<const short8*>(&Bs[(wc * 64 + n * 16 + fr) * 32 + qsw]);
    #pragma unroll
    for (int m = 0; m < 4; m++)
      #pragma unroll
      for (int n = 0; n < 4; n++)
        acc[m][n] = __builtin_amdgcn_mfma_f32_16x16x32_bf16(aF[m], bF[n], acc[m][n], 0, 0, 0);
    __syncthreads();
  }
  const int rq = (lane >> 4) * 4;
  float bias[4];
  #pragma unroll
  for (int n = 0; n < 4; n++)
    bias[n] = (kch == 0) ? b2[(size_t)e * Cdim + cBase + wc * 64 + n * 16 + fr] : 0.f;
  u16* yb = ybuf + (size_t)kch * NSLOT * Cdim;
  #pragma unroll
  for (int m = 0; m < 4; m++) {
    #pragma unroll
    for (int j = 0; j < 4; j++) {
      int rl = wr * 64 + m * 16 + rq + j;
      if (tokBase + rl < n_e) {
        u16* ob = yb + (size_t)(slotB + rl) * Cdim + cBase + wc * 64 + fr;
        #pragma unroll
        for (int n = 0; n < 4; n++)
          ob[n * 16] = f2bf(acc[m][n][j] + bias[n]);
      }
    }
  }
}

// ---------- gather ----------
__global__ __launch_bounds__(256)
void gather_kernel(const u16* __restrict__ ybuf, const int4* __restrict__ tokslot,
                   const float2* __restrict__ tokgate, const int* __restrict__ offs,
                   float* __restrict__ out) {
  const int gid = blockIdx.x * 256 + threadIdx.x;
  const int t = gid / 192;
  const int c4 = (gid - t * 192) * 4;
  int4 ts = tokslot[t];
  float2 g = tokgate[t];
  size_t s0 = (size_t)(offs[ts.x] + ts.y) * Cdim + c4;
  size_t s1 = (size_t)(offs[ts.z] + ts.w) * Cdim + c4;
  const size_t K1 = (size_t)NSLOT * Cdim;
  float acc0[4] = {}, acc1[4] = {};
  #pragma unroll
  for (int k = 0; k < KS2; k++) {
    ushort4v a = *reinterpret_cast<const ushort4v*>(ybuf + k * K1 + s0);
    ushort4v b = *reinterpret_cast<const ushort4v*>(ybuf + k * K1 + s1);
    #pragma unroll
    for (int j = 0; j < 4; j++) { acc0[j] += bf2f(a[j]); acc1[j] += bf2f(b[j]); }
  }
  float4 o;
  o.x = g.x * acc0[0] + g.y * acc1[0];
  o.y = g.x * acc0[1] + g.y * acc1[1];
  o.z = g.x * acc0[2] + g.y * acc1[2];
  o.w = g.x * acc0[3] + g.y * acc1[3];
  *reinterpret_cast<float4*>(out + (size_t)t * Cdim + c4) = o;
}

extern "C" void kernel_launch(void* const* d_in, const int* in_sizes, int n_in,
                              void* d_out, int out_size, void* d_ws, size_t ws_size,
                              hipStream_t stream) {
  const float* x        = (const float*)d_in[0];
  const float* router_w = (const float*)d_in[1];
  const float* probe_w  = (const float*)d_in[2];
  const float* emb      = (const float*)d_in[3];
  const float* fatigue  = (const float*)d_in[4];
  const float* energy   = (const float*)d_in[5];
  const float* wf1      = (const float*)d_in[6];
  const float* ws1      = (const float*)d_in[7];
  const float* hf1      = (const float*)d_in[8];
  const float* mg1      = (const float*)d_in[9];
  const float* b1       = (const float*)d_in[10];
  const float* wf2      = (const float*)d_in[11];
  const float* ws2      = (const float*)d_in[12];
  const float* hf2      = (const float*)d_in[13];
  const float* mg2      = (const float*)d_in[14];
  const float* b2       = (const float*)d_in[15];
  float* out = (float*)d_out;
  char* ws = (char*)d_ws;

  u16*    x16       = (u16*)(ws + OFF_XB);
  u16*    W1T       = (u16*)(ws + OFF_W1T);
  u16*    W2T       = (u16*)(ws + OFF_W2T);
  u16*    hbuf      = (u16*)(ws + OFF_HBUF);
  float*  xT        = (float*)(ws + OFF_XT);
  float*  part      = (float*)(ws + OFF_PART);
  u16*    ybuf      = (u16*)(ws + OFF_YB);
  int*    tok_list  = (int*)(ws + OFF_TOK);
  int*    rowmap    = (int*)(ws + OFF_RM);
  int*    nrows     = (int*)(ws + OFF_NR);
  int*    counts    = (int*)(ws + OFF_CNT);
  int*    offs      = (int*)(ws + OFF_OFFS);
  int4*   tokslot   = (int4*)(ws + OFF_TSLOT);
  float2* tokgate   = (float2*)(ws + OFF_TG);

  hipMemsetAsync(counts, 0, 64, stream);

  fused_pre1_kernel<<<768 + 2304, 256, 0, stream>>>(x, x16, xT,
                                                    wf1, ws1, hf1, mg1, W1T);
  logits_part_kernel<<<dim3(Ntok / 256, NCHUNK), 256, 0, stream>>>(xT, router_w, probe_w, part);
  router_fin_kernel<<<Ntok / 256, 256, 0, stream>>>(part, emb, fatigue, energy,
                                                    counts, tok_list, tokslot, tokgate);
  offsets_kernel<<<1, 64, 0, stream>>>(counts, offs, rowmap, nrows);
  fused_fc1p2_kernel<<<8 * SLX, 256, 0, stream>>>(x16, W1T, b1, counts, offs, tok_list,
                                                  rowmap, nrows, hbuf,
                                                  wf2, ws2, hf2, mg2, W2T);
  fc2_kernel<<<MAXROWS * 18, 256, 0, stream>>>(hbuf, W2T, b2, counts, offs,
                                               rowmap, nrows, ybuf);
  gather_kernel<<<Ntok * 192 / 256, 256, 0, stream>>>(ybuf, tokslot, tokgate, offs, out);
  (void)in_sizes; (void)n_in; (void)out_size; (void)ws_size;
}

// Round 22
// 337.201 us; speedup vs baseline: 1.1047x; 1.0071x over previous
//
#include <hip/hip_runtime.h>

typedef unsigned short u16;
typedef __attribute__((ext_vector_type(8))) short short8;
typedef __attribute__((ext_vector_type(8))) unsigned short ushort8;
typedef __attribute__((ext_vector_type(4))) unsigned short ushort4v;
typedef __attribute__((ext_vector_type(4))) float f32x4;

static constexpr int Cdim = 768;
static constexpr int Hdim = 3072;
static constexpr int Edim = 8;
static constexpr int Ntok = 4096;   // B*T
static constexpr int DRc  = 24;
static constexpr int NSLOT = Ntok * 2;  // 8192
static constexpr int NCHUNK = 8;
static constexpr int CCH = Cdim / NCHUNK;  // 96
static constexpr int KS2 = 3;              // fc2 split-K factor
static constexpr int KC2 = Hdim / KS2;     // 1024
static constexpr int MAXROWS = 71;         // sum ceil(n_e/128) <= 64+7
static constexpr int NFC1 = MAXROWS * 24;  // 1704 = 8*213
static constexpr int FCX = NFC1 / 8;       // 213 fc1 blocks per XCD
static constexpr int PRX = 2304 / 8;       // 288 prep blocks per XCD
static constexpr int SLX = FCX + PRX;      // 501 slots per XCD (stage B)
static constexpr int PXX = 768 / 8;        // 96 prep_x blocks per XCD
static constexpr int SLA = PXX + PRX;      // 384 slots per XCD (stage A)

// ---- workspace layout (bytes) ----
static constexpr size_t OFF_XB   = 0;                          // x bf16: 6,291,456
static constexpr size_t OFF_W1T  = 6291456;                    // [E][H][C] bf16: 37,748,736
static constexpr size_t OFF_W2T  = 44040192;                   // [E][C][H] bf16: 37,748,736
static constexpr size_t OFF_HBUF = 81788928;                   // 8192*3072*2 = 50,331,648
// xT/part alias hbuf (dead before fc1); ybuf aliases W1T (dead after fc1)
static constexpr size_t OFF_XT   = OFF_HBUF;                   // f32 [C][N]: 12,582,912
static constexpr size_t OFF_PART = OFF_HBUF + 12582912;        // f32 [8][33][N]: 4,325,376
static constexpr size_t OFF_YB   = OFF_W1T;                    // bf16 [3][NSLOT][C]: 37,748,736
static constexpr size_t OFF_TOK  = 132120576;                  // E*N*4 = 131,072
static constexpr size_t OFF_RM   = 132251648;                  // rowmap int[71]
static constexpr size_t OFF_NR   = 132252160;                  // nrows int[1]
static constexpr size_t OFF_CNT  = 132382720;                  // 8*4
static constexpr size_t OFF_OFFS = 132382752;                  // 8*4
static constexpr size_t OFF_TSLOT= 132382784;                  // int4 [Ntok]: 65,536
static constexpr size_t OFF_TG   = 132448320;                  // float2 [Ntok]: 32,768

__device__ __forceinline__ u16 f2bf(float f) {
  unsigned u = __builtin_bit_cast(unsigned, f);
  u += 0x7fffu + ((u >> 16) & 1u);          // round-to-nearest-even
  return (u16)(u >> 16);
}

__device__ __forceinline__ float bf2f(u16 v) {
  unsigned u = ((unsigned)v) << 16;
  return __builtin_bit_cast(float, u);
}

// async global->LDS, 16B per lane (HW: wave-uniform LDS base + lane*16)
__device__ __forceinline__ void gld16(const u16* g, u16* l) {
  __builtin_amdgcn_global_load_lds((const __attribute__((address_space(1))) unsigned int*)g,
                                   (__attribute__((address_space(3))) unsigned int*)l,
                                   16, 0, 0);
}

// bijective chunked XCD remap (m204)
__device__ __forceinline__ int xcd_remap(int p, int nwg) {
  int q = nwg >> 3, rem = nwg & 7;
  int x = p & 7, i = p >> 3;
  return (x < rem ? x * (q + 1) : rem * (q + 1) + (x - rem) * q) + i;
}

// ---------- prep W tile body: 64r x 128c, u32 column-pair LDS ----------
template<int R, int CCOL>
__device__ __forceinline__ void prep_wt_body(const float* __restrict__ wf,
                                             const float* __restrict__ wsl,
                                             const float* __restrict__ hf, float m,
                                             u16* __restrict__ outw, int e, int r0, int c0,
                                             unsigned* lds) {
  const size_t base = (size_t)e * R * CCOL;
  const int t = threadIdx.x;
  {
    const int rp = t >> 5;            // 0..7
    const int col4 = (t & 31) * 4;    // 0..124
    const int c2w = (t & 31) * 2;
    #pragma unroll
    for (int i = 0; i < 8; i++) {
      int r = i * 8 + rp;
      size_t idx = base + (size_t)(r0 + r) * CCOL + c0 + col4;
      float4 a = *(const float4*)(wf + idx);
      float4 b = *(const float4*)(wsl + idx);
      float4 h = *(const float4*)(hf + idx);
      unsigned u0 = (unsigned)f2bf(fmaf(m, b.x, a.x) + h.x)
                  | ((unsigned)f2bf(fmaf(m, b.y, a.y) + h.y) << 16);
      unsigned u1 = (unsigned)f2bf(fmaf(m, b.z, a.z) + h.z)
                  | ((unsigned)f2bf(fmaf(m, b.w, a.w) + h.w) << 16);
      lds[c2w * 65 + r] = u0;
      lds[(c2w + 1) * 65 + r] = u1;
    }
  }
  __syncthreads();
  {
    const int c2 = t >> 2;            // 0..63 (column pair)
    const int rseg = (t & 3) * 16;    // 16-row segment
    const unsigned* cp = lds + c2 * 65 + rseg;
    unsigned in4[16];
    #pragma unroll
    for (int j = 0; j < 4; j++)
      *reinterpret_cast<uint4*>(&in4[j * 4]) = *reinterpret_cast<const uint4*>(cp + j * 4);
    unsigned lo[8], hi[8];
    #pragma unroll
    for (int j = 0; j < 8; j++) {
      unsigned a = in4[2 * j], b = in4[2 * j + 1];
      lo[j] = (a & 0xffffu) | (b << 16);
      hi[j] = (a >> 16) | (b & 0xffff0000u);
    }
    size_t ob = ((size_t)e * CCOL + c0 + 2 * c2) * R + r0 + rseg;   // u16 units
    *reinterpret_cast<uint4*>(outw + ob)          = *reinterpret_cast<const uint4*>(&lo[0]);
    *reinterpret_cast<uint4*>(outw + ob + 8)      = *reinterpret_cast<const uint4*>(&lo[4]);
    *reinterpret_cast<uint4*>(outw + ob + R)      = *reinterpret_cast<const uint4*>(&hi[0]);
    *reinterpret_cast<uint4*>(outw + ob + R + 8)  = *reinterpret_cast<const uint4*>(&hi[4]);
  }
}

// ---------- fused: prep_x2 + prep_wt layer1, per-XCD Bresenham interleave ----------
__global__ __launch_bounds__(256)
void fused_pre1_kernel(const float* __restrict__ x, u16* __restrict__ x16,
                       float* __restrict__ xT,
                       const float* __restrict__ wf1, const float* __restrict__ ws1,
                       const float* __restrict__ hf1, const float* __restrict__ mg1,
                       u16* __restrict__ W1T) {
  __shared__ unsigned lsbuf[64 * 65];      // 16,640 B (union: float tile / u32 pairs)
  const int p = blockIdx.x;
  const int xcd = p & 7, q = p >> 3;       // slot within XCD, q in [0, SLA)
  const int jx = (q * PXX) / SLA;          // prep_x count before slot q
  const bool isPx = ((q + 1) * PXX) / SLA > jx;
  if (isPx) {
    // ---- prep_x2: x -> bf16 [N][C] and f32 transpose [C][N] ----
    int bid = xcd * PXX + jx;              // logical prep_x id
    float* tile = reinterpret_cast<float*>(lsbuf);    // [64][65]
    const int c0 = (bid % 12) * 64;
    const int t0 = (bid / 12) * 64;
    const int tid = threadIdx.x;
    const int row = tid >> 4, col = (tid & 15) * 4;
    #pragma unroll
    for (int i = 0; i < 4; i++) {
      int r = row + i * 16;
      size_t idx = (size_t)(t0 + r) * Cdim + c0 + col;
      float4 v = *(const float4*)(x + idx);
      tile[r * 65 + col + 0] = v.x; tile[r * 65 + col + 1] = v.y;
      tile[r * 65 + col + 2] = v.z; tile[r * 65 + col + 3] = v.w;
      ushort4v o = { f2bf(v.x), f2bf(v.y), f2bf(v.z), f2bf(v.w) };
      *reinterpret_cast<ushort4v*>(x16 + idx) = o;
    }
    __syncthreads();
    const int c = tid >> 2, tg = (tid & 3) * 16;
    #pragma unroll
    for (int qq = 0; qq < 4; qq++) {
      float4 w;
      w.x = tile[(tg + qq * 4 + 0) * 65 + c];
      w.y = tile[(tg + qq * 4 + 1) * 65 + c];
      w.z = tile[(tg + qq * 4 + 2) * 65 + c];
      w.w = tile[(tg + qq * 4 + 3) * 65 + c];
      *reinterpret_cast<float4*>(xT + (size_t)(c0 + c) * Ntok + t0 + tg + qq * 4) = w;
    }
  } else {
    // ---- prep_wt layer1: [E][C][H] -> W1T [E][H][C] ----
    int bid = xcd * PRX + (q - jx);        // logical prep id, XCD-chunked
    int e = bid / 288, rem = bid % 288;
    int xx = rem % 12, yy = rem / 12;
    prep_wt_body<768, 3072>(wf1, ws1, hf1, mg1[e], W1T, e, xx * 64, yy * 128, lsbuf);
  }
}

// ---------- router part 1 ----------
__global__ __launch_bounds__(256)
void logits_part_kernel(const float* __restrict__ xT, const float* __restrict__ router_w,
                        const float* __restrict__ probe_w, float* __restrict__ part) {
  const int t = blockIdx.x * 256 + threadIdx.x;
  const int cB = blockIdx.y * CCH;
  float racc[Edim] = {};
  float pacc[DRc] = {};
  float sacc = 0.f;
  for (int ci = 0; ci < CCH; ci++) {
    int c = cB + ci;
    float xv = xT[(size_t)c * Ntok + t];
    sacc += xv;
    #pragma unroll
    for (int ee = 0; ee < Edim; ee++) racc[ee] = fmaf(xv, router_w[ee * Cdim + c], racc[ee]);
    #pragma unroll
    for (int d = 0; d < DRc; d++) pacc[d] = fmaf(xv, probe_w[d * Cdim + c], pacc[d]);
  }
  float* pb = part + (size_t)blockIdx.y * 33 * Ntok + t;
  #pragma unroll
  for (int ee = 0; ee < Edim; ee++) pb[(size_t)ee * Ntok] = racc[ee];
  #pragma unroll
  for (int d = 0; d < DRc; d++) pb[(size_t)(8 + d) * Ntok] = pacc[d];
  pb[(size_t)32 * Ntok] = sacc;
}

// ---------- router part 2 ----------
__global__ __launch_bounds__(256)
void router_fin_kernel(const float* __restrict__ part, const float* __restrict__ emb,
                       const float* __restrict__ fatigue, const float* __restrict__ energy,
                       int* __restrict__ counts, int* __restrict__ tok_list,
                       int4* __restrict__ tokslot, float2* __restrict__ tokgate) {
  const int t = blockIdx.x * 256 + threadIdx.x;
  float v[33];
  #pragma unroll
  for (int o = 0; o < 33; o++) {
    float s = 0.f;
    #pragma unroll
    for (int ch = 0; ch < NCHUNK; ch++)
      s += part[((size_t)ch * 33 + o) * Ntok + t];
    v[o] = s;
  }
  const float* racc = v;
  const float* pacc = v + 8;
  float proxy = v[32] / 768.f;
  float pn2 = 0.f;
  #pragma unroll
  for (int d = 0; d < DRc; d++) pn2 += pacc[d] * pacc[d];
  float pnorm = sqrtf(pn2);
  float logitv[Edim];
  #pragma unroll
  for (int ee = 0; ee < Edim; ee++) {
    float g2 = 0.f, dote = 0.f;
    #pragma unroll
    for (int d = 0; d < DRc; d++) {
      float ev = emb[ee * DRc + d];
      g2 += ev * ev;
      dote += pacc[d] * ev;
    }
    float gain = sqrtf(g2);
    float align = dote / (fmaxf(pnorm, 1e-12f) * fmaxf(gain, 1e-12f));
    logitv[ee] = racc[ee] + 0.02f * proxy * (1.f + gain) + 0.02f * align
               + 0.1f * energy[ee] - 0.1f * fatigue[ee];
  }
  int e0 = 0; float b0v = logitv[0];
  #pragma unroll
  for (int ee = 1; ee < Edim; ee++) if (logitv[ee] > b0v) { b0v = logitv[ee]; e0 = ee; }
  int e1 = -1; float b1v = -3.4e38f;
  #pragma unroll
  for (int ee = 0; ee < Edim; ee++) if (ee != e0 && logitv[ee] > b1v) { b1v = logitv[ee]; e1 = ee; }
  float texp = expf(b1v - b0v);
  float g0 = 1.f / (1.f + texp);
  float g1 = texp / (1.f + texp);
  int p0 = atomicAdd(&counts[e0], 1);
  tok_list[e0 * Ntok + p0] = t;
  int p1 = atomicAdd(&counts[e1], 1);
  tok_list[e1 * Ntok + p1] = t;
  tokslot[t] = make_int4(e0, p0, e1, p1);
  tokgate[t] = make_float2(g0, g1);
}

// ---------- offsets + compacted row worklist ----------
__global__ void offsets_kernel(const int* __restrict__ counts, int* __restrict__ offs,
                               int* __restrict__ rowmap, int* __restrict__ nrows) {
  if (threadIdx.x == 0) {
    int r = 0, nr = 0;
    for (int e = 0; e < Edim; e++) {
      offs[e] = r;
      int ne = counts[e];
      for (int tb = 0; tb < ne; tb += 128) rowmap[nr++] = (e << 16) | (tb >> 7);
      r += ne;
    }
    nrows[0] = nr;
  }
}

// ---------- fused: fc1 + prep_wt layer2, per-XCD Bresenham interleave ----------
__global__ __launch_bounds__(256)
void fused_fc1p2_kernel(const u16* __restrict__ x16, const u16* __restrict__ W1T,
                        const float* __restrict__ b1, const int* __restrict__ counts,
                        const int* __restrict__ offs, const int* __restrict__ tok_list,
                        const int* __restrict__ rowmap, const int* __restrict__ nrows,
                        u16* __restrict__ h_buf,
                        const float* __restrict__ wf2, const float* __restrict__ ws2,
                        const float* __restrict__ hf2, const float* __restrict__ mg2,
                        u16* __restrict__ W2T) {
  __shared__ unsigned smem4[4224];          // 16,896 B union
  const int p = blockIdx.x;
  const int xcd = p & 7, q = p >> 3;        // slot within XCD
  const int j = (q * FCX) / SLX;            // fc1 count before slot q (Bresenham)
  const bool isFc1 = ((q + 1) * FCX) / SLX > j;
  if (!isFc1) {
    // ---- prep_wt layer2: [E][H][C] -> W2T [E][C][H] ----
    int bid = xcd * PRX + (q - j);          // logical prep id, XCD-chunked
    int e = bid / 288, rem = bid % 288;
    int xx = rem % 48, yy = rem / 48;
    prep_wt_body<3072, 768>(wf2, ws2, hf2, mg2[e], W2T, e, xx * 64, yy * 128, smem4);
    return;
  }
  // ---- fc1: h = relu(x @ W1 + b1)^2, 128x128 tile, single-buffer ----
  u16* As = reinterpret_cast<u16*>(smem4);          // 4096 u16
  u16* Bs = As + 4096;                              // 4096 u16
  int* toks = reinterpret_cast<int*>(As + 8192);    // 128 int
  const int l = xcd * FCX + j;              // logical fc1 id, XCD-chunked
  const int r = l / 24;
  if (r >= nrows[0]) return;
  const int hB = l % 24;
  const int rm = rowmap[r];
  const int e = rm >> 16;
  const int tokBase = (rm & 0xffff) << 7;
  const int n_e = counts[e];
  const int hBase = hB * 128;
  const int tid = threadIdx.x;
  if (tid < 128) {
    int s = tokBase + tid;
    toks[tid] = (s < n_e) ? tok_list[e * Ntok + s] : 0;
  }
  __syncthreads();
  const int lane = tid & 63, wv = tid >> 6;
  const int wr = wv >> 1, wc = wv & 1;
  const int sRow = lane >> 2, sSlot = lane & 3;
  const int kbOff = (sSlot ^ ((sRow >> 1) & 3)) * 8;
  const int rA0 = wv * 16 + sRow, rA1 = 64 + rA0;
  const u16* pA0 = x16 + (size_t)toks[rA0] * Cdim + kbOff;
  const u16* pA1 = x16 + (size_t)toks[rA1] * Cdim + kbOff;
  const u16* pB0 = W1T + ((size_t)e * Hdim + hBase + rA0) * Cdim + kbOff;
  const u16* pB1 = W1T + ((size_t)e * Hdim + hBase + rA1) * Cdim + kbOff;
  const int stOff = wv * 512 + lane * 8;
  const int fr = lane & 15;
  const int qsw = (((lane >> 4) ^ ((fr >> 1) & 3))) * 8;
  f32x4 acc[4][4] = {};
  for (int it = 0; it < 24; it++) {
    int k0 = it * 32;
    gld16(pA0 + k0, As + stOff);
    gld16(pA1 + k0, As + 2048 + stOff);
    gld16(pB0 + k0, Bs + stOff);
    gld16(pB1 + k0, Bs + 2048 + stOff);
    __syncthreads();
    short8 aF[4], bF[4];
    #pragma unroll
    for (int m = 0; m < 4; m++)
      aF[m] = *reinterpret_cast<const short8*>(As + (wr * 64 + m * 16 + fr) * 32 + qsw);
    #pragma unroll
    for (int n = 0; n < 4; n++)
      bF[n] = *reinterpret_cast<const short8*>(Bs + (wc * 64 + n * 16 + fr) * 32 + qsw);
    #pragma unroll
    for (int m = 0; m < 4; m++)
      #pragma unroll
      for (int n = 0; n < 4; n++)
        acc[m][n] = __builtin_amdgcn_mfma_f32_16x16x32_bf16(aF[m], bF[n], acc[m][n], 0, 0, 0);
    __syncthreads();
  }
  const int rq = (lane >> 4) * 4;
  float bias[4];
  #pragma unroll
  for (int n = 0; n < 4; n++) bias[n] = b1[(size_t)e * Hdim + hBase + wc * 64 + n * 16 + fr];
  const int rowB = offs[e] + tokBase;
  #pragma unroll
  for (int m = 0; m < 4; m++) {
    #pragma unroll
    for (int j2 = 0; j2 < 4; j2++) {
      int rl = wr * 64 + m * 16 + rq + j2;
      if (tokBase + rl < n_e) {
        size_t rb = (size_t)(rowB + rl) * Hdim + hBase + wc * 64 + fr;
        #pragma unroll
        for (int n = 0; n < 4; n++) {
          float v = fmaxf(acc[m][n][j2] + bias[n], 0.f);
          h_buf[rb + n * 16] = f2bf(v * v);
        }
      }
    }
  }
}

// ---------- fc2: ybuf[kch][slot] = h @ W2T[kch] (+b2 on kch0), 128x128, split-K3 ----------
__global__ __launch_bounds__(256)
void fc2_kernel(const u16* __restrict__ h_buf, const u16* __restrict__ W2T,
                const float* __restrict__ b2, const int* __restrict__ counts,
                const int* __restrict__ offs, const int* __restrict__ rowmap,
                const int* __restrict__ nrows, u16* __restrict__ ybuf) {
  const int l = xcd_remap(blockIdx.x, MAXROWS * 18);
  const int r = l / 18;
  if (r >= nrows[0]) return;
  const int xb = l % 18;
  const int rm = rowmap[r];
  const int e = rm >> 16;
  const int tokBase = (rm & 0xffff) << 7;
  const int n_e = counts[e];
  const int kch = xb / 6;                  // 0..KS2-1
  const int cBase = (xb % 6) * 128;
  const size_t kOff = (size_t)kch * KC2;
  __shared__ u16 As[4096];
  __shared__ u16 Bs[4096];
  const int tid = threadIdx.x;
  const int lane = tid & 63, wv = tid >> 6;
  const int wr = wv >> 1, wc = wv & 1;
  const int sRow = lane >> 2, sSlot = lane & 3;
  const int kbOff = (sSlot ^ ((sRow >> 1) & 3)) * 8;
  const int rA0 = wv * 16 + sRow, rA1 = 64 + rA0;
  const int slotB = offs[e] + tokBase;
  const int s0 = min(slotB + rA0, NSLOT - 1);
  const int s1 = min(slotB + rA1, NSLOT - 1);
  const u16* pA0 = h_buf + (size_t)s0 * Hdim + kOff + kbOff;
  const u16* pA1 = h_buf + (size_t)s1 * Hdim + kOff + kbOff;
  const u16* pB0 = W2T + ((size_t)e * Cdim + cBase + rA0) * Hdim + kOff + kbOff;
  const u16* pB1 = W2T + ((size_t)e * Cdim + cBase + rA1) * Hdim + kOff + kbOff;
  const int stOff = wv * 512 + lane * 8;
  const int fr = lane & 15;
  const int qsw = (((lane >> 4) ^ ((fr >> 1) & 3))) * 8;
  f32x4 acc[4][4] = {};
  for (int it = 0; it < KC2 / 32; it++) {
    int k0 = it * 32;
    gld16(pA0 + k0, &As[stOff]);
    gld16(pA1 + k0, &As[2048 + stOff]);
    gld16(pB0 + k0, &Bs[stOff]);
    gld16(pB1 + k0, &Bs[2048 + stOff]);
    __syncthreads();
    short8 aF[4], bF[4];
    #pragma unroll
    for (int m = 0; m < 4; m++)
      aF[m] = *reinterpret_cast<const short8*>(&As[(wr * 64 + m * 16 + fr) * 32 + qsw]);
    #pragma unroll
    for (int n = 0; n < 4; n++)
      bF[n] = *reinterpret_cast<const short8*>(&Bs[(wc * 64 + n * 16 + fr) * 32 + qsw]);
    #pragma unroll
    for (int m = 0; m < 4; m++)
      #pragma unroll
      for (int n = 0; n < 4; n++)
        acc[m][n] = __builtin_amdgcn_mfma_f32_16x16x32_bf16(aF[m], bF[n], acc[m][n], 0, 0, 0);
    __syncthreads();
  }
  const int rq = (lane >> 4) * 4;
  float bias[4];
  #pragma unroll
  for (int n = 0; n < 4; n++)
    bias[n] = (kch == 0) ? b2[(size_t)e * Cdim + cBase + wc * 64 + n * 16 + fr] : 0.f;
  u16* yb = ybuf + (size_t)kch * NSLOT * Cdim;
  #pragma unroll
  for (int m = 0; m < 4; m++) {
    #pragma unroll
    for (int j = 0; j < 4; j++) {
      int rl = wr * 64 + m * 16 + rq + j;
      if (tokBase + rl < n_e) {
        u16* ob = yb + (size_t)(slotB + rl) * Cdim + cBase + wc * 64 + fr;
        #pragma unroll
        for (int n = 0; n < 4; n++)
          ob[n * 16] = f2bf(acc[m][n][j] + bias[n]);
      }
    }
  }
}

// ---------- gather ----------
__global__ __launch_bounds__(256)
void gather_kernel(const u16* __restrict__ ybuf, const int4* __restrict__ tokslot,
                   const float2* __restrict__ tokgate, const int* __restrict__ offs,
                   float* __restrict__ out) {
  const int gid = blockIdx.x * 256 + threadIdx.x;
  const int t = gid / 192;
  const int c4 = (gid - t * 192) * 4;
  int4 ts = tokslot[t];
  float2 g = tokgate[t];
  size_t s0 = (size_t)(offs[ts.x] + ts.y) * Cdim + c4;
  size_t s1 = (size_t)(offs[ts.z] + ts.w) * Cdim + c4;
  const size_t K1 = (size_t)NSLOT * Cdim;
  float acc0[4] = {}, acc1[4] = {};
  #pragma unroll
  for (int k = 0; k < KS2; k++) {
    ushort4v a = *reinterpret_cast<const ushort4v*>(ybuf + k * K1 + s0);
    ushort4v b = *reinterpret_cast<const ushort4v*>(ybuf + k * K1 + s1);
    #pragma unroll
    for (int j = 0; j < 4; j++) { acc0[j] += bf2f(a[j]); acc1[j] += bf2f(b[j]); }
  }
  float4 o;
  o.x = g.x * acc0[0] + g.y * acc1[0];
  o.y = g.x * acc0[1] + g.y * acc1[1];
  o.z = g.x * acc0[2] + g.y * acc1[2];
  o.w = g.x * acc0[3] + g.y * acc1[3];
  *reinterpret_cast<float4*>(out + (size_t)t * Cdim + c4) = o;
}

extern "C" void kernel_launch(void* const* d_in, const int* in_sizes, int n_in,
                              void* d_out, int out_size, void* d_ws, size_t ws_size,
                              hipStream_t stream) {
  const float* x        = (const float*)d_in[0];
  const float* router_w = (const float*)d_in[1];
  const float* probe_w  = (const float*)d_in[2];
  const float* emb      = (const float*)d_in[3];
  const float* fatigue  = (const float*)d_in[4];
  const float* energy   = (const float*)d_in[5];
  const float* wf1      = (const float*)d_in[6];
  const float* ws1      = (const float*)d_in[7];
  const float* hf1      = (const float*)d_in[8];
  const float* mg1      = (const float*)d_in[9];
  const float* b1       = (const float*)d_in[10];
  const float* wf2      = (const float*)d_in[11];
  const float* ws2      = (const float*)d_in[12];
  const float* hf2      = (const float*)d_in[13];
  const float* mg2      = (const float*)d_in[14];
  const float* b2       = (const float*)d_in[15];
  float* out = (float*)d_out;
  char* ws = (char*)d_ws;

  u16*    x16       = (u16*)(ws + OFF_XB);
  u16*    W1T       = (u16*)(ws + OFF_W1T);
  u16*    W2T       = (u16*)(ws + OFF_W2T);
  u16*    hbuf      = (u16*)(ws + OFF_HBUF);
  float*  xT        = (float*)(ws + OFF_XT);
  float*  part      = (float*)(ws + OFF_PART);
  u16*    ybuf      = (u16*)(ws + OFF_YB);
  int*    tok_list  = (int*)(ws + OFF_TOK);
  int*    rowmap    = (int*)(ws + OFF_RM);
  int*    nrows     = (int*)(ws + OFF_NR);
  int*    counts    = (int*)(ws + OFF_CNT);
  int*    offs      = (int*)(ws + OFF_OFFS);
  int4*   tokslot   = (int4*)(ws + OFF_TSLOT);
  float2* tokgate   = (float2*)(ws + OFF_TG);

  hipMemsetAsync(counts, 0, 64, stream);

  fused_pre1_kernel<<<8 * SLA, 256, 0, stream>>>(x, x16, xT,
                                                 wf1, ws1, hf1, mg1, W1T);
  logits_part_kernel<<<dim3(Ntok / 256, NCHUNK), 256, 0, stream>>>(xT, router_w, probe_w, part);
  router_fin_kernel<<<Ntok / 256, 256, 0, stream>>>(part, emb, fatigue, energy,
                                                    counts, tok_list, tokslot, tokgate);
  offsets_kernel<<<1, 64, 0, stream>>>(counts, offs, rowmap, nrows);
  fused_fc1p2_kernel<<<8 * SLX, 256, 0, stream>>>(x16, W1T, b1, counts, offs, tok_list,
                                                  rowmap, nrows, hbuf,
                                                  wf2, ws2, hf2, mg2, W2T);
  fc2_kernel<<<MAXROWS * 18, 256, 0, stream>>>(hbuf, W2T, b2, counts, offs,
                                               rowmap, nrows, ybuf);
  gather_kernel<<<Ntok * 192 / 256, 256, 0, stream>>>(ybuf, tokslot, tokgate, offs, out);
  (void)in_sizes; (void)n_in; (void)out_size; (void)ws_size;
}

// Round 23
// 324.898 us; speedup vs baseline: 1.1465x; 1.0379x over previous
//
#include <hip/hip_runtime.h>

typedef unsigned short u16;
typedef __attribute__((ext_vector_type(8))) short short8;
typedef __attribute__((ext_vector_type(8))) unsigned short ushort8;
typedef __attribute__((ext_vector_type(4))) unsigned short ushort4v;
typedef __attribute__((ext_vector_type(4))) float f32x4;

static constexpr int Cdim = 768;
static constexpr int Hdim = 3072;
static constexpr int Edim = 8;
static constexpr int Ntok = 4096;   // B*T
static constexpr int DRc  = 24;
static constexpr int NSLOT = Ntok * 2;  // 8192
static constexpr int NCHUNK = 8;
static constexpr int CCH = Cdim / NCHUNK;  // 96
static constexpr int KS2 = 3;              // fc2 split-K factor
static constexpr int KC2 = Hdim / KS2;     // 1024
static constexpr int MAXROWS = 71;         // sum ceil(n_e/128) <= 64+7
static constexpr int NFC1 = MAXROWS * 24;  // 1704 = 8*213
static constexpr int FCX = NFC1 / 8;       // 213 fc1 blocks per XCD
static constexpr int PRX = 2304 / 8;       // 288 prep blocks per XCD
static constexpr int SLX = FCX + PRX;      // 501 slots per XCD (stage B)
static constexpr int PXX = 768 / 8;        // 96 prep_x blocks per XCD
static constexpr int SLA = PXX + PRX;      // 384 slots per XCD (stage A)

// ---- workspace layout (bytes) ----
static constexpr size_t OFF_XB   = 0;                          // x bf16: 6,291,456
static constexpr size_t OFF_W1T  = 6291456;                    // [E][H][C] bf16: 37,748,736
static constexpr size_t OFF_W2T  = 44040192;                   // [E][C][H] bf16: 37,748,736
static constexpr size_t OFF_HBUF = 81788928;                   // 8192*3072*2 = 50,331,648
// xT/part alias hbuf (dead before fc1); ybuf aliases W1T (dead after fc1)
static constexpr size_t OFF_XT   = OFF_HBUF;                   // f32 [C][N]: 12,582,912
static constexpr size_t OFF_PART = OFF_HBUF + 12582912;        // f32 [8][33][N]: 4,325,376
static constexpr size_t OFF_YB   = OFF_W1T;                    // bf16 [3][NSLOT][C]: 37,748,736
static constexpr size_t OFF_TOK  = 132120576;                  // E*N*4 = 131,072
static constexpr size_t OFF_CNT  = 132382720;                  // 8*4
static constexpr size_t OFF_TSLOT= 132382784;                  // int4 [Ntok]: 65,536
static constexpr size_t OFF_TG   = 132448320;                  // float2 [Ntok]: 32,768

__device__ __forceinline__ u16 f2bf(float f) {
  unsigned u = __builtin_bit_cast(unsigned, f);
  u += 0x7fffu + ((u >> 16) & 1u);          // round-to-nearest-even
  return (u16)(u >> 16);
}

__device__ __forceinline__ float bf2f(u16 v) {
  unsigned u = ((unsigned)v) << 16;
  return __builtin_bit_cast(float, u);
}

// async global->LDS, 16B per lane (HW: wave-uniform LDS base + lane*16)
__device__ __forceinline__ void gld16(const u16* g, u16* l) {
  __builtin_amdgcn_global_load_lds((const __attribute__((address_space(1))) unsigned int*)g,
                                   (__attribute__((address_space(3))) unsigned int*)l,
                                   16, 0, 0);
}

// bijective chunked XCD remap (m204)
__device__ __forceinline__ int xcd_remap(int p, int nwg) {
  int q = nwg >> 3, rem = nwg & 7;
  int x = p & 7, i = p >> 3;
  return (x < rem ? x * (q + 1) : rem * (q + 1) + (x - rem) * q) + i;
}

// decode logical row index r -> (expert e, tokBase, slot offset) from counts.
// Returns false if r >= total rows. Also yields offs[e] (slot prefix).
__device__ __forceinline__ bool decode_row(const int* __restrict__ counts, int r,
                                           int& e_out, int& tokBase, int& slotOff) {
  int run = 0;
  #pragma unroll
  for (int e = 0; e < Edim; e++) {
    int ne = counts[e];
    int nb = (ne + 127) >> 7;
    if (r < nb) { e_out = e; tokBase = r << 7; slotOff = run; return true; }
    r -= nb;
    run += ne;
  }
  return false;
}

// ---------- prep W tile body: 64r x 128c, u32 column-pair LDS ----------
template<int R, int CCOL>
__device__ __forceinline__ void prep_wt_body(const float* __restrict__ wf,
                                             const float* __restrict__ wsl,
                                             const float* __restrict__ hf, float m,
                                             u16* __restrict__ outw, int e, int r0, int c0,
                                             unsigned* lds) {
  const size_t base = (size_t)e * R * CCOL;
  const int t = threadIdx.x;
  {
    const int rp = t >> 5;            // 0..7
    const int col4 = (t & 31) * 4;    // 0..124
    const int c2w = (t & 31) * 2;
    #pragma unroll
    for (int i = 0; i < 8; i++) {
      int r = i * 8 + rp;
      size_t idx = base + (size_t)(r0 + r) * CCOL + c0 + col4;
      float4 a = *(const float4*)(wf + idx);
      float4 b = *(const float4*)(wsl + idx);
      float4 h = *(const float4*)(hf + idx);
      unsigned u0 = (unsigned)f2bf(fmaf(m, b.x, a.x) + h.x)
                  | ((unsigned)f2bf(fmaf(m, b.y, a.y) + h.y) << 16);
      unsigned u1 = (unsigned)f2bf(fmaf(m, b.z, a.z) + h.z)
                  | ((unsigned)f2bf(fmaf(m, b.w, a.w) + h.w) << 16);
      lds[c2w * 65 + r] = u0;
      lds[(c2w + 1) * 65 + r] = u1;
    }
  }
  __syncthreads();
  {
    const int c2 = t >> 2;            // 0..63 (column pair)
    const int rseg = (t & 3) * 16;    // 16-row segment
    const unsigned* cp = lds + c2 * 65 + rseg;
    unsigned in4[16];
    #pragma unroll
    for (int j = 0; j < 4; j++)
      *reinterpret_cast<uint4*>(&in4[j * 4]) = *reinterpret_cast<const uint4*>(cp + j * 4);
    unsigned lo[8], hi[8];
    #pragma unroll
    for (int j = 0; j < 8; j++) {
      unsigned a = in4[2 * j], b = in4[2 * j + 1];
      lo[j] = (a & 0xffffu) | (b << 16);
      hi[j] = (a >> 16) | (b & 0xffff0000u);
    }
    size_t ob = ((size_t)e * CCOL + c0 + 2 * c2) * R + r0 + rseg;   // u16 units
    *reinterpret_cast<uint4*>(outw + ob)          = *reinterpret_cast<const uint4*>(&lo[0]);
    *reinterpret_cast<uint4*>(outw + ob + 8)      = *reinterpret_cast<const uint4*>(&lo[4]);
    *reinterpret_cast<uint4*>(outw + ob + R)      = *reinterpret_cast<const uint4*>(&hi[0]);
    *reinterpret_cast<uint4*>(outw + ob + R + 8)  = *reinterpret_cast<const uint4*>(&hi[4]);
  }
}

// ---------- fused: prep_x2 + prep_wt layer1, per-XCD Bresenham interleave ----------
__global__ __launch_bounds__(256)
void fused_pre1_kernel(const float* __restrict__ x, u16* __restrict__ x16,
                       float* __restrict__ xT,
                       const float* __restrict__ wf1, const float* __restrict__ ws1,
                       const float* __restrict__ hf1, const float* __restrict__ mg1,
                       u16* __restrict__ W1T) {
  __shared__ unsigned lsbuf[64 * 65];      // 16,640 B (union: float tile / u32 pairs)
  const int p = blockIdx.x;
  const int xcd = p & 7, q = p >> 3;       // slot within XCD, q in [0, SLA)
  const int jx = (q * PXX) / SLA;          // prep_x count before slot q
  const bool isPx = ((q + 1) * PXX) / SLA > jx;
  if (isPx) {
    // ---- prep_x2: x -> bf16 [N][C] and f32 transpose [C][N] ----
    int bid = xcd * PXX + jx;              // logical prep_x id
    float* tile = reinterpret_cast<float*>(lsbuf);    // [64][65]
    const int c0 = (bid % 12) * 64;
    const int t0 = (bid / 12) * 64;
    const int tid = threadIdx.x;
    const int row = tid >> 4, col = (tid & 15) * 4;
    #pragma unroll
    for (int i = 0; i < 4; i++) {
      int r = row + i * 16;
      size_t idx = (size_t)(t0 + r) * Cdim + c0 + col;
      float4 v = *(const float4*)(x + idx);
      tile[r * 65 + col + 0] = v.x; tile[r * 65 + col + 1] = v.y;
      tile[r * 65 + col + 2] = v.z; tile[r * 65 + col + 3] = v.w;
      ushort4v o = { f2bf(v.x), f2bf(v.y), f2bf(v.z), f2bf(v.w) };
      *reinterpret_cast<ushort4v*>(x16 + idx) = o;
    }
    __syncthreads();
    const int c = tid >> 2, tg = (tid & 3) * 16;
    #pragma unroll
    for (int qq = 0; qq < 4; qq++) {
      float4 w;
      w.x = tile[(tg + qq * 4 + 0) * 65 + c];
      w.y = tile[(tg + qq * 4 + 1) * 65 + c];
      w.z = tile[(tg + qq * 4 + 2) * 65 + c];
      w.w = tile[(tg + qq * 4 + 3) * 65 + c];
      *reinterpret_cast<float4*>(xT + (size_t)(c0 + c) * Ntok + t0 + tg + qq * 4) = w;
    }
  } else {
    // ---- prep_wt layer1: [E][C][H] -> W1T [E][H][C] ----
    int bid = xcd * PRX + (q - jx);        // logical prep id, XCD-chunked
    int e = bid / 288, rem = bid % 288;
    int xx = rem % 12, yy = rem / 12;
    prep_wt_body<768, 3072>(wf1, ws1, hf1, mg1[e], W1T, e, xx * 64, yy * 128, lsbuf);
  }
}

// ---------- router part 1 (also zeroes counts for the next kernel) ----------
__global__ __launch_bounds__(256)
void logits_part_kernel(const float* __restrict__ xT, const float* __restrict__ router_w,
                        const float* __restrict__ probe_w, float* __restrict__ part,
                        int* __restrict__ counts) {
  if (blockIdx.x == 0 && blockIdx.y == 0 && threadIdx.x < Edim)
    counts[threadIdx.x] = 0;               // ordered before router_fin's atomics
  const int t = blockIdx.x * 256 + threadIdx.x;
  const int cB = blockIdx.y * CCH;
  float racc[Edim] = {};
  float pacc[DRc] = {};
  float sacc = 0.f;
  for (int ci = 0; ci < CCH; ci++) {
    int c = cB + ci;
    float xv = xT[(size_t)c * Ntok + t];
    sacc += xv;
    #pragma unroll
    for (int ee = 0; ee < Edim; ee++) racc[ee] = fmaf(xv, router_w[ee * Cdim + c], racc[ee]);
    #pragma unroll
    for (int d = 0; d < DRc; d++) pacc[d] = fmaf(xv, probe_w[d * Cdim + c], pacc[d]);
  }
  float* pb = part + (size_t)blockIdx.y * 33 * Ntok + t;
  #pragma unroll
  for (int ee = 0; ee < Edim; ee++) pb[(size_t)ee * Ntok] = racc[ee];
  #pragma unroll
  for (int d = 0; d < DRc; d++) pb[(size_t)(8 + d) * Ntok] = pacc[d];
  pb[(size_t)32 * Ntok] = sacc;
}

// ---------- router part 2 ----------
__global__ __launch_bounds__(256)
void router_fin_kernel(const float* __restrict__ part, const float* __restrict__ emb,
                       const float* __restrict__ fatigue, const float* __restrict__ energy,
                       int* __restrict__ counts, int* __restrict__ tok_list,
                       int4* __restrict__ tokslot, float2* __restrict__ tokgate) {
  const int t = blockIdx.x * 256 + threadIdx.x;
  float v[33];
  #pragma unroll
  for (int o = 0; o < 33; o++) {
    float s = 0.f;
    #pragma unroll
    for (int ch = 0; ch < NCHUNK; ch++)
      s += part[((size_t)ch * 33 + o) * Ntok + t];
    v[o] = s;
  }
  const float* racc = v;
  const float* pacc = v + 8;
  float proxy = v[32] / 768.f;
  float pn2 = 0.f;
  #pragma unroll
  for (int d = 0; d < DRc; d++) pn2 += pacc[d] * pacc[d];
  float pnorm = sqrtf(pn2);
  float logitv[Edim];
  #pragma unroll
  for (int ee = 0; ee < Edim; ee++) {
    float g2 = 0.f, dote = 0.f;
    #pragma unroll
    for (int d = 0; d < DRc; d++) {
      float ev = emb[ee * DRc + d];
      g2 += ev * ev;
      dote += pacc[d] * ev;
    }
    float gain = sqrtf(g2);
    float align = dote / (fmaxf(pnorm, 1e-12f) * fmaxf(gain, 1e-12f));
    logitv[ee] = racc[ee] + 0.02f * proxy * (1.f + gain) + 0.02f * align
               + 0.1f * energy[ee] - 0.1f * fatigue[ee];
  }
  int e0 = 0; float b0v = logitv[0];
  #pragma unroll
  for (int ee = 1; ee < Edim; ee++) if (logitv[ee] > b0v) { b0v = logitv[ee]; e0 = ee; }
  int e1 = -1; float b1v = -3.4e38f;
  #pragma unroll
  for (int ee = 0; ee < Edim; ee++) if (ee != e0 && logitv[ee] > b1v) { b1v = logitv[ee]; e1 = ee; }
  float texp = expf(b1v - b0v);
  float g0 = 1.f / (1.f + texp);
  float g1 = texp / (1.f + texp);
  int p0 = atomicAdd(&counts[e0], 1);
  tok_list[e0 * Ntok + p0] = t;
  int p1 = atomicAdd(&counts[e1], 1);
  tok_list[e1 * Ntok + p1] = t;
  tokslot[t] = make_int4(e0, p0, e1, p1);
  tokgate[t] = make_float2(g0, g1);
}

// ---------- fused: fc1 + prep_wt layer2, per-XCD Bresenham interleave ----------
__global__ __launch_bounds__(256)
void fused_fc1p2_kernel(const u16* __restrict__ x16, const u16* __restrict__ W1T,
                        const float* __restrict__ b1, const int* __restrict__ counts,
                        const int* __restrict__ tok_list, u16* __restrict__ h_buf,
                        const float* __restrict__ wf2, const float* __restrict__ ws2,
                        const float* __restrict__ hf2, const float* __restrict__ mg2,
                        u16* __restrict__ W2T) {
  __shared__ unsigned smem4[4224];          // 16,896 B union
  const int p = blockIdx.x;
  const int xcd = p & 7, q = p >> 3;        // slot within XCD
  const int j = (q * FCX) / SLX;            // fc1 count before slot q (Bresenham)
  const bool isFc1 = ((q + 1) * FCX) / SLX > j;
  if (!isFc1) {
    // ---- prep_wt layer2: [E][H][C] -> W2T [E][C][H] ----
    int bid = xcd * PRX + (q - j);          // logical prep id, XCD-chunked
    int e = bid / 288, rem = bid % 288;
    int xx = rem % 48, yy = rem / 48;
    prep_wt_body<3072, 768>(wf2, ws2, hf2, mg2[e], W2T, e, xx * 64, yy * 128, smem4);
    return;
  }
  // ---- fc1: h = relu(x @ W1 + b1)^2, 128x128 tile, single-buffer ----
  u16* As = reinterpret_cast<u16*>(smem4);          // 4096 u16
  u16* Bs = As + 4096;                              // 4096 u16
  int* toks = reinterpret_cast<int*>(As + 8192);    // 128 int
  const int l = xcd * FCX + j;              // logical fc1 id, XCD-chunked
  const int r = l / 24;
  int e, tokBase, slotOff;
  if (!decode_row(counts, r, e, tokBase, slotOff)) return;
  const int hB = l % 24;
  const int n_e = counts[e];
  const int hBase = hB * 128;
  const int tid = threadIdx.x;
  if (tid < 128) {
    int s = tokBase + tid;
    toks[tid] = (s < n_e) ? tok_list[e * Ntok + s] : 0;
  }
  __syncthreads();
  const int lane = tid & 63, wv = tid >> 6;
  const int wr = wv >> 1, wc = wv & 1;
  const int sRow = lane >> 2, sSlot = lane & 3;
  const int kbOff = (sSlot ^ ((sRow >> 1) & 3)) * 8;
  const int rA0 = wv * 16 + sRow, rA1 = 64 + rA0;
  const u16* pA0 = x16 + (size_t)toks[rA0] * Cdim + kbOff;
  const u16* pA1 = x16 + (size_t)toks[rA1] * Cdim + kbOff;
  const u16* pB0 = W1T + ((size_t)e * Hdim + hBase + rA0) * Cdim + kbOff;
  const u16* pB1 = W1T + ((size_t)e * Hdim + hBase + rA1) * Cdim + kbOff;
  const int stOff = wv * 512 + lane * 8;
  const int fr = lane & 15;
  const int qsw = (((lane >> 4) ^ ((fr >> 1) & 3))) * 8;
  f32x4 acc[4][4] = {};
  for (int it = 0; it < 24; it++) {
    int k0 = it * 32;
    gld16(pA0 + k0, As + stOff);
    gld16(pA1 + k0, As + 2048 + stOff);
    gld16(pB0 + k0, Bs + stOff);
    gld16(pB1 + k0, Bs + 2048 + stOff);
    __syncthreads();
    short8 aF[4], bF[4];
    #pragma unroll
    for (int m = 0; m < 4; m++)
      aF[m] = *reinterpret_cast<const short8*>(As + (wr * 64 + m * 16 + fr) * 32 + qsw);
    #pragma unroll
    for (int n = 0; n < 4; n++)
      bF[n] = *reinterpret_cast<const short8*>(Bs + (wc * 64 + n * 16 + fr) * 32 + qsw);
    #pragma unroll
    for (int m = 0; m < 4; m++)
      #pragma unroll
      for (int n = 0; n < 4; n++)
        acc[m][n] = __builtin_amdgcn_mfma_f32_16x16x32_bf16(aF[m], bF[n], acc[m][n], 0, 0, 0);
    __syncthreads();
  }
  const int rq = (lane >> 4) * 4;
  float bias[4];
  #pragma unroll
  for (int n = 0; n < 4; n++) bias[n] = b1[(size_t)e * Hdim + hBase + wc * 64 + n * 16 + fr];
  const int rowB = slotOff + tokBase;
  #pragma unroll
  for (int m = 0; m < 4; m++) {
    #pragma unroll
    for (int j2 = 0; j2 < 4; j2++) {
      int rl = wr * 64 + m * 16 + rq + j2;
      if (tokBase + rl < n_e) {
        size_t rb = (size_t)(rowB + rl) * Hdim + hBase + wc * 64 + fr;
        #pragma unroll
        for (int n = 0; n < 4; n++) {
          float v = fmaxf(acc[m][n][j2] + bias[n], 0.f);
          h_buf[rb + n * 16] = f2bf(v * v);
        }
      }
    }
  }
}

// ---------- fc2: ybuf[kch][slot] = h @ W2T[kch] (+b2 on kch0), 128x128, split-K3 ----------
__global__ __launch_bounds__(256)
void fc2_kernel(const u16* __restrict__ h_buf, const u16* __restrict__ W2T,
                const float* __restrict__ b2, const int* __restrict__ counts,
                u16* __restrict__ ybuf) {
  const int l = xcd_remap(blockIdx.x, MAXROWS * 18);
  const int r = l / 18;
  int e, tokBase, slotOff;
  if (!decode_row(counts, r, e, tokBase, slotOff)) return;
  const int xb = l % 18;
  const int n_e = counts[e];
  const int kch = xb / 6;                  // 0..KS2-1
  const int cBase = (xb % 6) * 128;
  const size_t kOff = (size_t)kch * KC2;
  __shared__ u16 As[4096];
  __shared__ u16 Bs[4096];
  const int tid = threadIdx.x;
  const int lane = tid & 63, wv = tid >> 6;
  const int wr = wv >> 1, wc = wv & 1;
  const int sRow = lane >> 2, sSlot = lane & 3;
  const int kbOff = (sSlot ^ ((sRow >> 1) & 3)) * 8;
  const int rA0 = wv * 16 + sRow, rA1 = 64 + rA0;
  const int slotB = slotOff + tokBase;
  const int s0 = min(slotB + rA0, NSLOT - 1);
  const int s1 = min(slotB + rA1, NSLOT - 1);
  const u16* pA0 = h_buf + (size_t)s0 * Hdim + kOff + kbOff;
  const u16* pA1 = h_buf + (size_t)s1 * Hdim + kOff + kbOff;
  const u16* pB0 = W2T + ((size_t)e * Cdim + cBase + rA0) * Hdim + kOff + kbOff;
  const u16* pB1 = W2T + ((size_t)e * Cdim + cBase + rA1) * Hdim + kOff + kbOff;
  const int stOff = wv * 512 + lane * 8;
  const int fr = lane & 15;
  const int qsw = (((lane >> 4) ^ ((fr >> 1) & 3))) * 8;
  f32x4 acc[4][4] = {};
  for (int it = 0; it < KC2 / 32; it++) {
    int k0 = it * 32;
    gld16(pA0 + k0, &As[stOff]);
    gld16(pA1 + k0, &As[2048 + stOff]);
    gld16(pB0 + k0, &Bs[stOff]);
    gld16(pB1 + k0, &Bs[2048 + stOff]);
    __syncthreads();
    short8 aF[4], bF[4];
    #pragma unroll
    for (int m = 0; m < 4; m++)
      aF[m] = *reinterpret_cast<const short8*>(&As[(wr * 64 + m * 16 + fr) * 32 + qsw]);
    #pragma unroll
    for (int n = 0; n < 4; n++)
      bF[n] = *reinterpret_cast<const short8*>(&Bs[(wc * 64 + n * 16 + fr) * 32 + qsw]);
    #pragma unroll
    for (int m = 0; m < 4; m++)
      #pragma unroll
      for (int n = 0; n < 4; n++)
        acc[m][n] = __builtin_amdgcn_mfma_f32_16x16x32_bf16(aF[m], bF[n], acc[m][n], 0, 0, 0);
    __syncthreads();
  }
  const int rq = (lane >> 4) * 4;
  float bias[4];
  #pragma unroll
  for (int n = 0; n < 4; n++)
    bias[n] = (kch == 0) ? b2[(size_t)e * Cdim + cBase + wc * 64 + n * 16 + fr] : 0.f;
  u16* yb = ybuf + (size_t)kch * NSLOT * Cdim;
  #pragma unroll
  for (int m = 0; m < 4; m++) {
    #pragma unroll
    for (int j = 0; j < 4; j++) {
      int rl = wr * 64 + m * 16 + rq + j;
      if (tokBase + rl < n_e) {
        u16* ob = yb + (size_t)(slotB + rl) * Cdim + cBase + wc * 64 + fr;
        #pragma unroll
        for (int n = 0; n < 4; n++)
          ob[n * 16] = f2bf(acc[m][n][j] + bias[n]);
      }
    }
  }
}

// ---------- gather ----------
__global__ __launch_bounds__(256)
void gather_kernel(const u16* __restrict__ ybuf, const int4* __restrict__ tokslot,
                   const float2* __restrict__ tokgate, const int* __restrict__ counts,
                   float* __restrict__ out) {
  const int gid = blockIdx.x * 256 + threadIdx.x;
  const int t = gid / 192;
  const int c4 = (gid - t * 192) * 4;
  int4 ts = tokslot[t];
  float2 g = tokgate[t];
  int o0 = 0, o1 = 0, run = 0;
  #pragma unroll
  for (int e = 0; e < Edim; e++) {
    if (e == ts.x) o0 = run;
    if (e == ts.z) o1 = run;
    run += counts[e];
  }
  size_t s0 = (size_t)(o0 + ts.y) * Cdim + c4;
  size_t s1 = (size_t)(o1 + ts.w) * Cdim + c4;
  const size_t K1 = (size_t)NSLOT * Cdim;
  float acc0[4] = {}, acc1[4] = {};
  #pragma unroll
  for (int k = 0; k < KS2; k++) {
    ushort4v a = *reinterpret_cast<const ushort4v*>(ybuf + k * K1 + s0);
    ushort4v b = *reinterpret_cast<const ushort4v*>(ybuf + k * K1 + s1);
    #pragma unroll
    for (int j = 0; j < 4; j++) { acc0[j] += bf2f(a[j]); acc1[j] += bf2f(b[j]); }
  }
  float4 o;
  o.x = g.x * acc0[0] + g.y * acc1[0];
  o.y = g.x * acc0[1] + g.y * acc1[1];
  o.z = g.x * acc0[2] + g.y * acc1[2];
  o.w = g.x * acc0[3] + g.y * acc1[3];
  *reinterpret_cast<float4*>(out + (size_t)t * Cdim + c4) = o;
}

extern "C" void kernel_launch(void* const* d_in, const int* in_sizes, int n_in,
                              void* d_out, int out_size, void* d_ws, size_t ws_size,
                              hipStream_t stream) {
  const float* x        = (const float*)d_in[0];
  const float* router_w = (const float*)d_in[1];
  const float* probe_w  = (const float*)d_in[2];
  const float* emb      = (const float*)d_in[3];
  const float* fatigue  = (const float*)d_in[4];
  const float* energy   = (const float*)d_in[5];
  const float* wf1      = (const float*)d_in[6];
  const float* ws1      = (const float*)d_in[7];
  const float* hf1      = (const float*)d_in[8];
  const float* mg1      = (const float*)d_in[9];
  const float* b1       = (const float*)d_in[10];
  const float* wf2      = (const float*)d_in[11];
  const float* ws2      = (const float*)d_in[12];
  const float* hf2      = (const float*)d_in[13];
  const float* mg2      = (const float*)d_in[14];
  const float* b2       = (const float*)d_in[15];
  float* out = (float*)d_out;
  char* ws = (char*)d_ws;

  u16*    x16       = (u16*)(ws + OFF_XB);
  u16*    W1T       = (u16*)(ws + OFF_W1T);
  u16*    W2T       = (u16*)(ws + OFF_W2T);
  u16*    hbuf      = (u16*)(ws + OFF_HBUF);
  float*  xT        = (float*)(ws + OFF_XT);
  float*  part      = (float*)(ws + OFF_PART);
  u16*    ybuf      = (u16*)(ws + OFF_YB);
  int*    tok_list  = (int*)(ws + OFF_TOK);
  int*    counts    = (int*)(ws + OFF_CNT);
  int4*   tokslot   = (int4*)(ws + OFF_TSLOT);
  float2* tokgate   = (float2*)(ws + OFF_TG);

  fused_pre1_kernel<<<8 * SLA, 256, 0, stream>>>(x, x16, xT,
                                                 wf1, ws1, hf1, mg1, W1T);
  logits_part_kernel<<<dim3(Ntok / 256, NCHUNK), 256, 0, stream>>>(xT, router_w, probe_w,
                                                                   part, counts);
  router_fin_kernel<<<Ntok / 256, 256, 0, stream>>>(part, emb, fatigue, energy,
                                                    counts, tok_list, tokslot, tokgate);
  fused_fc1p2_kernel<<<8 * SLX, 256, 0, stream>>>(x16, W1T, b1, counts, tok_list, hbuf,
                                                  wf2, ws2, hf2, mg2, W2T);
  fc2_kernel<<<MAXROWS * 18, 256, 0, stream>>>(hbuf, W2T, b2, counts, ybuf);
  gather_kernel<<<Ntok * 192 / 256, 256, 0, stream>>>(ybuf, tokslot, tokgate, counts, out);
  (void)in_sizes; (void)n_in; (void)out_size; (void)ws_size;
}